// Round 13
// baseline (142.611 us; speedup 1.0000x reference)
//
#include <hip/hip_runtime.h>
#include <math.h>

// V=50000, E=128, D=256, L=400, B=64
#define BB 64
#define DD 256
#define LL 400
#define VV 50000
#define EE 128
#define NB 782   // ceil(VV/64)

typedef __attribute__((ext_vector_type(8))) short short8v;
typedef __attribute__((ext_vector_type(4))) short short4v;
typedef __attribute__((ext_vector_type(4))) float f32x4;

__device__ __forceinline__ float sigmoidf_(float x){ return 1.0f/(1.0f+expf(-x)); }

__device__ __forceinline__ short f2bf(float f){
    unsigned u = __builtin_bit_cast(unsigned, f);
    u += 0x7fffu + ((u>>16)&1u);
    return (short)(u>>16);
}

// actT layout (transposed activations [row][batch], 64 floats per row):
//   rows    0..255 : x
//   rows  256..767 : weighted context (wc)
//   rows 768..1023 : h_new
//   rows 1024..1279: c_new
#define ROW_X   0
#define ROW_WC  256
#define ROW_H   768
#define ROW_C   1024

// 8 independent column loads + pin + 8 FMAs (keeps 8 loads in flight; the
// compiler otherwise sinks each load to its use -> 1 load in flight, ~500cyc/it)
#define DOT8(col, wptr, kk, acc) { \
    float a0_=(col)[((kk)+0)*64], a1_=(col)[((kk)+1)*64], a2_=(col)[((kk)+2)*64], a3_=(col)[((kk)+3)*64], \
          a4_=(col)[((kk)+4)*64], a5_=(col)[((kk)+5)*64], a6_=(col)[((kk)+6)*64], a7_=(col)[((kk)+7)*64]; \
    asm volatile("" : "+v"(a0_),"+v"(a1_),"+v"(a2_),"+v"(a3_),"+v"(a4_),"+v"(a5_),"+v"(a6_),"+v"(a7_)); \
    acc += a0_*(wptr)[(kk)+0] + a1_*(wptr)[(kk)+1] + a2_*(wptr)[(kk)+2] + a3_*(wptr)[(kk)+3] \
         + a4_*(wptr)[(kk)+4] + a5_*(wptr)[(kk)+5] + a6_*(wptr)[(kk)+6] + a7_*(wptr)[(kk)+7]; }

__device__ __forceinline__ float dot4v(f32x4 a, f32x4 b){
    return a[0]*b[0] + a[1]*b[1] + a[2]*b[2] + a[3]*b[3];
}

// ============ FRONT STAGE 1: x, h, c (+ score prep) ================================
// grid (DD,4) x 256. y0: x -> actT rows 0..255. y1/y2: reduced h/c -> WhT/WcT0.
// y3: Wb fragment-order pack + u,v2.
__global__ __launch_bounds__(256) void k_front1(
    const int* __restrict__ inp, const float* __restrict__ hh, const float* __restrict__ hc,
    const float* __restrict__ prev, const float* __restrict__ emb_w,
    const float* __restrict__ lin_w, const float* __restrict__ lin_b,
    const float* __restrict__ rhw, const float* __restrict__ rhb,
    const float* __restrict__ rcw, const float* __restrict__ rcb,
    const int* __restrict__ step_p,
    const float* __restrict__ wk_w, const float* __restrict__ wk_b,
    const float* __restrict__ cov_w, const float* __restrict__ cov_b,
    float* __restrict__ actT, float* __restrict__ WhT, float* __restrict__ WcT0,
    short* __restrict__ Wb, float* __restrict__ u, float* __restrict__ v2)
{
    const int d = blockIdx.x, y = blockIdx.y, t = threadIdx.x;
    const int b = t >> 2, kq = t & 3;
    __shared__ float lw[640];
    __shared__ float red[256];

    if (y == 3){
        const float* row = wk_w + (size_t)d*512;
        float su=0.f, sv=0.f;
        for (int j=t; j<512; j+=256){
            float wv = row[j];
            Wb[(size_t)(j>>3)*2048 + d*8 + (j&7)] = f2bf(wv);
            su += wv*cov_w[j];
            sv += wv*cov_b[j];
        }
        float* rs = lw;
        float* rv = red;
        rs[t]=su; rv[t]=sv; __syncthreads();
        for (int s=128;s>0;s>>=1){ if(t<s){rs[t]+=rs[t+s]; rv[t]+=rv[t+s];} __syncthreads(); }
        if (t==0){ u[d]=rs[0]; v2[d]=rv[0] + wk_b[d]; }
        return;
    }

    if (y == 0){
        if (t < 160) ((f32x4*)lw)[t] = ((const f32x4*)(lin_w + (size_t)d*640))[t];
        __syncthreads();
        const f32x4* lw4 = (const f32x4*)lw;
        const f32x4* er4 = (const f32x4*)(emb_w + (size_t)inp[b]*EE);
        const f32x4* pv4 = (const f32x4*)(prev + (size_t)b*512);
        float acc = 0.f;
        for (int i=kq; i<160; i+=16){
            f32x4 v0 = (i    < 32) ? er4[i]    : pv4[i-32];
            f32x4 v1 = (i+4  < 32) ? er4[i+4]  : pv4[i-28];
            f32x4 v2_ = pv4[i-24];   // i+8 >= 32 always when i>=24; guard below
            f32x4 v3 = pv4[i-20];
            if (i+8  < 32) v2_ = er4[i+8];
            if (i+12 < 32) v3 = er4[i+12];
            asm volatile("" : "+v"(v0),"+v"(v1),"+v"(v2_),"+v"(v3));
            acc += dot4v(v0, lw4[i]) + dot4v(v1, lw4[i+4])
                 + dot4v(v2_, lw4[i+8]) + dot4v(v3, lw4[i+12]);
        }
        acc += __shfl_xor(acc,1); acc += __shfl_xor(acc,2);
        if (kq == 0) actT[(ROW_X + d)*64 + b] = lin_b[d] + acc;
        return;
    }

    const float* src  = (y==1) ? hh  : hc;
    float*       dstT = (y==1) ? WhT : WcT0;
    if (*step_p == 0){
        const float* wrow = ((y==1) ? rhw : rcw) + (size_t)d*512;
        const float  bias = ((y==1) ? rhb : rcb)[d];
        if (t < 128) ((f32x4*)lw)[t] = ((const f32x4*)wrow)[t];
        __syncthreads();
        const f32x4* lw4 = (const f32x4*)lw;
        const f32x4* s0 = (const f32x4*)(src + (size_t)b*DD);
        const f32x4* s1 = (const f32x4*)(src + (size_t)BB*DD + (size_t)b*DD);
        float acc = 0.f;
        for (int i=kq; i<128; i+=16){
            f32x4 v0 = (i    < 64) ? s0[i]    : s1[i-64];
            f32x4 v1 = (i+4  < 64) ? s0[i+4]  : s1[i-60];
            f32x4 v2_ = (i+8 < 64) ? s0[i+8]  : s1[i-56];
            f32x4 v3 = (i+12 < 64) ? s0[i+12] : s1[i-52];
            asm volatile("" : "+v"(v0),"+v"(v1),"+v"(v2_),"+v"(v3));
            acc += dot4v(v0, lw4[i]) + dot4v(v1, lw4[i+4])
                 + dot4v(v2_, lw4[i+8]) + dot4v(v3, lw4[i+12]);
        }
        acc += __shfl_xor(acc,1); acc += __shfl_xor(acc,2);
        if (kq == 0){
            float a = bias + acc;
            dstT[d*64 + b] = a>0.f ? a : 0.f;
        }
    } else {
        if (t < 64) dstT[d*64 + t] = src[(size_t)t*DD + d];
    }
}

// ============ FRONT STAGE 2: gates + LSTM (8-deep load groups) ======================
__global__ __launch_bounds__(256) void k_gl(
    const float* __restrict__ actT, const float* __restrict__ WhT, const float* __restrict__ WcT0,
    const float* __restrict__ w_ih, const float* __restrict__ w_hh,
    const float* __restrict__ b_ih, const float* __restrict__ b_hh,
    float* __restrict__ o_h, float* __restrict__ o_c, float* __restrict__ actT_out)
{
    const int d = blockIdx.x, t = threadIdx.x;
    const int b = t & 63, gi = t >> 6;
    __shared__ float wih[4][256];
    __shared__ float whh[4][256];
    __shared__ float gl[4][64];

    const int gr = gi*DD + d;
    ((f32x4*)&wih[gi][0])[b] = ((const f32x4*)(w_ih + (size_t)gr*DD))[b];
    ((f32x4*)&whh[gi][0])[b] = ((const f32x4*)(w_hh + (size_t)gr*DD))[b];
    __syncthreads();

    const float* xcol = actT + ROW_X*64 + b;
    const float* hcol = WhT + b;
    float a0=0.f, a1=0.f;
    for (int kk=0; kk<256; kk+=8){
        DOT8(xcol, &wih[gi][0], kk, a0);
        DOT8(hcol, &whh[gi][0], kk, a1);
    }
    gl[gi][b] = a0 + a1 + b_ih[gr] + b_hh[gr];
    __syncthreads();

    if (t < 64){
        float iv = sigmoidf_(gl[0][t]);
        float fv = sigmoidf_(gl[1][t]);
        float gv = tanhf(gl[2][t]);
        float ov = sigmoidf_(gl[3][t]);
        float cn = fv*WcT0[d*64 + t] + iv*gv;
        float hn = ov*tanhf(cn);
        o_c[(size_t)t*DD + d] = cn;
        o_h[(size_t)t*DD + d] = hn;
        actT_out[(ROW_C + d)*64 + t] = cn;
        actT_out[(ROW_H + d)*64 + t] = hn;
    }
}

// ============ FRONT STAGE 3: Q (8-deep load groups over actT h/c rows) =============
__global__ __launch_bounds__(256) void k_q2(
    const float* __restrict__ actT,
    const float* __restrict__ wq_w, const float* __restrict__ wq_b,
    float* __restrict__ Qs)
{
    const int d = blockIdx.x, t = threadIdx.x;
    const int b = t & 63, w = t >> 6;
    __shared__ float lw[512];
    __shared__ float red[4][64];
    if (t < 128) ((f32x4*)lw)[t] = ((const f32x4*)(wq_w + (size_t)d*512))[t];
    __syncthreads();
    const float* col = actT + ROW_H*64 + b;   // rows 768..1279 = [h(256), c(256)]
    float acc = 0.f;
    const int k0 = w*128;
    for (int kk=k0; kk<k0+128; kk+=8)
        DOT8(col, lw, kk, acc);
    red[w][b] = acc; __syncthreads();
    if (t < 64)
        Qs[(size_t)t*DD + d] = tanhf(wq_b[d] + red[0][t]+red[1][t]+red[2][t]+red[3][t]) * 0.0625f;
}

// ---------------- score: MFMA bf16, K-chunked reg pipeline, packed-B ----------------
#define SC_MFMA(KS, BF) \
  { const int cc_ = (KS)*4 + qw; \
    short8v a0_ = *(const short8v*)&As[lr*512 + ((cc_ ^ (lr&7))<<3)]; \
    short8v a1_ = *(const short8v*)&As[(16+lr)*512 + ((cc_ ^ (lr&7))<<3)]; \
    acc0 = __builtin_amdgcn_mfma_f32_16x16x32_bf16(a0_, BF, acc0, 0,0,0); \
    acc1 = __builtin_amdgcn_mfma_f32_16x16x32_bf16(a1_, BF, acc1, 0,0,0); }

#define SC_CHUNK(KC, B0,B1,B2,B3) \
    SC_MFMA((KC)*4+0, B0); SC_MFMA((KC)*4+1, B1); \
    SC_MFMA((KC)*4+2, B2); SC_MFMA((KC)*4+3, B3);

__global__ __launch_bounds__(1024, 4) void k_score_mfma(
    const float* __restrict__ enc, const short* __restrict__ Wb,
    const float* __restrict__ u, const float* __restrict__ v2,
    const float* __restrict__ Qs, const float* __restrict__ cov,
    const float* __restrict__ pmask, float* __restrict__ score)
{
    const int b  = blockIdx.y;
    const int l0 = blockIdx.x * 32;
    const int tid = threadIdx.x;
    const int wave = tid >> 6, lane = tid & 63;
    const int qw = lane >> 4, lr = lane & 15;
    const int col = wave*16 + lr;

    __shared__ __align__(16) short As[32*512];
    __shared__ float Red[16][32];

    const short* bp = Wb + (size_t)qw*2048 + col*8;
    short8v c0 = *(const short8v*)(bp +  0*8192);
    short8v c1 = *(const short8v*)(bp +  1*8192);
    short8v c2 = *(const short8v*)(bp +  2*8192);
    short8v c3 = *(const short8v*)(bp +  3*8192);

    const int arow = tid >> 5;
    const int af   = tid & 31;
    const bool aval = (l0 + arow) < LL;
    const float4* aptr = (const float4*)(enc + ((size_t)(b*LL + (aval ? l0+arow : 0)))*512);
    float4 areg[4];
    #pragma unroll
    for (int j=0; j<4; j++)
        areg[j] = aval ? aptr[af + j*32] : float4{0.f,0.f,0.f,0.f};

    #pragma unroll
    for (int j=0; j<4; j++){
        const int fi   = af + j*32;
        const int c    = fi >> 1;
        const int half = fi & 1;
        const int cs   = c ^ (arow & 7);
        short4v t4;
        t4[0]=f2bf(areg[j].x); t4[1]=f2bf(areg[j].y);
        t4[2]=f2bf(areg[j].z); t4[3]=f2bf(areg[j].w);
        *(short4v*)&As[arow*512 + cs*8 + half*4] = t4;
    }
    __syncthreads();

    f32x4 acc0 = f32x4{0.f,0.f,0.f,0.f};
    f32x4 acc1 = f32x4{0.f,0.f,0.f,0.f};

    short8v n0 = *(const short8v*)(bp +  4*8192);
    short8v n1 = *(const short8v*)(bp +  5*8192);
    short8v n2 = *(const short8v*)(bp +  6*8192);
    short8v n3 = *(const short8v*)(bp +  7*8192);
    SC_CHUNK(0, c0,c1,c2,c3);
    asm volatile("" : "+v"(n0),"+v"(n1),"+v"(n2),"+v"(n3));

    c0 = *(const short8v*)(bp +  8*8192);
    c1 = *(const short8v*)(bp +  9*8192);
    c2 = *(const short8v*)(bp + 10*8192);
    c3 = *(const short8v*)(bp + 11*8192);
    SC_CHUNK(1, n0,n1,n2,n3);
    asm volatile("" : "+v"(c0),"+v"(c1),"+v"(c2),"+v"(c3));

    n0 = *(const short8v*)(bp + 12*8192);
    n1 = *(const short8v*)(bp + 13*8192);
    n2 = *(const short8v*)(bp + 14*8192);
    n3 = *(const short8v*)(bp + 15*8192);
    SC_CHUNK(2, c0,c1,c2,c3);
    asm volatile("" : "+v"(n0),"+v"(n1),"+v"(n2),"+v"(n3));

    SC_CHUNK(3, n0,n1,n2,n3);

    const float qv = Qs[b*DD + col];
    const float uv = u[col];
    const float vv = v2[col];
    #pragma unroll
    for (int rf=0; rf<2; rf++){
        const f32x4 acc = rf ? acc1 : acc0;
        const int rbase = l0 + rf*16 + qw*4;
        float cv[4];
        if (rbase < LL){
            float4 c4v = *(const float4*)(cov + (size_t)b*LL + rbase);
            cv[0]=c4v.x; cv[1]=c4v.y; cv[2]=c4v.z; cv[3]=c4v.w;
        } else { cv[0]=cv[1]=cv[2]=cv[3]=0.f; }
        #pragma unroll
        for (int r=0; r<4; r++){
            float s = qv * tanhf(acc[r] + cv[r]*uv + vv);
            s += __shfl_xor(s,1); s += __shfl_xor(s,2);
            s += __shfl_xor(s,4); s += __shfl_xor(s,8);
            if (lr == 0) Red[wave][rf*16 + qw*4 + r] = s;
        }
    }
    __syncthreads();
    if (tid < 32){
        int l = l0 + tid;
        if (l < LL){
            float s = 0.f;
            #pragma unroll
            for (int w2=0; w2<16; w2++) s += Red[w2][tid];
            score[b*LL + l] = (pmask[b*LL+l] > 0.f) ? s : -1e18f;
        }
    }
}

// ---------------- fused softmax(L) + weighted context ------------------------------
__global__ __launch_bounds__(512) void k_wcsm(
    const float* __restrict__ score, const float* __restrict__ cov_in,
    const float* __restrict__ enc,
    float* __restrict__ attn_out, float* __restrict__ cov_out, float* __restrict__ wc)
{
    const int b = blockIdx.y, ch = blockIdx.x;
    const int t = threadIdx.x;
    __shared__ float sc[LL];
    __shared__ float red[512];

    float v = (t < LL) ? score[b*LL + t] : -INFINITY;
    red[t] = v; __syncthreads();
    for (int s=256;s>0;s>>=1){ if(t<s) red[t]=fmaxf(red[t],red[t+s]); __syncthreads(); }
    float m = red[0]; __syncthreads();
    float e = (t < LL) ? expf(v - m) : 0.f;
    if (t < LL) sc[t] = e;
    red[t] = e; __syncthreads();
    for (int s=256;s>0;s>>=1){ if(t<s) red[t]+=red[t+s]; __syncthreads(); }
    const float inv = 1.0f / red[0];

    const int l0 = ch * (LL/16);
    float s = 0.f;
    #pragma unroll 5
    for (int l=l0; l<l0+LL/16; ++l)
        s += sc[l] * enc[((size_t)(b*LL+l))*512 + t];
    atomicAdd(&wc[b*512 + t], s * inv);

    if (ch == 0 && t < LL){
        attn_out[b*LL + t] = sc[t] * inv;
        cov_out[b*LL + t]  = cov_in[b*LL + t];
    }
}

// ---------------- transpose wc -> actT rows 256..767 (LDS tile) --------------------
__global__ __launch_bounds__(256) void k_tr(const float* __restrict__ wc,
                                            float* __restrict__ actT)
{
    const int j0 = blockIdx.x * 64;   // 8 blocks cover 512 j's
    __shared__ float tile[64][65];
    const int t = threadIdx.x;
    const int c = t & 63, r0 = t >> 6;
    #pragma unroll
    for (int bb = r0; bb < 64; bb += 4)
        tile[bb][c] = wc[(size_t)bb*512 + j0 + c];
    __syncthreads();
    #pragma unroll
    for (int jj = r0; jj < 64; jj += 4)
        actT[(ROW_WC + j0 + jj)*64 + c] = tile[c][jj];
}

// ============ pregen (+ p_gen in block 0), 8-deep load groups ======================
__global__ __launch_bounds__(256) void k_pregen(
    const float* __restrict__ actT,
    const float* __restrict__ pre_w, const float* __restrict__ pre_b,
    const float* __restrict__ pgen_w, const float* __restrict__ pgen_b,
    short* __restrict__ pregenb, float* __restrict__ pgen_out)
{
    const int d = blockIdx.x, t = threadIdx.x;
    const int b = t & 63, w = t >> 6;
    __shared__ float pw[768];
    __shared__ float red[4][64];
    if (t < 192) ((f32x4*)pw)[t] = ((const f32x4*)(pre_w + (size_t)d*768))[t];
    __syncthreads();
    // pre dot: rows 256..1023 = [wc(512), h(256)] contiguous
    const float* col = actT + ROW_WC*64 + b;
    float acc = 0.f;
    const int k0 = w*192;
    for (int kk=k0; kk<k0+192; kk+=8)
        DOT8(col, pw, kk, acc);
    red[w][b] = acc; __syncthreads();
    if (t < 64)
        pregenb[(size_t)t*DD + d] = f2bf(pre_b[d] + red[0][t]+red[1][t]+red[2][t]+red[3][t]);

    if (blockIdx.x == 0){
        __syncthreads();
        // p_gen: rows 0..1279 = [x, wc, h, c] — matches pgen_w order
        const float* colx = actT + b;
        float p = 0.f;
        const int j0 = w*320;
        for (int jj=j0; jj<j0+320; jj+=8)
            DOT8(colx, pgen_w, jj, p);
        red[w][b] = p; __syncthreads();
        if (t < 64)
            pgen_out[t] = sigmoidf_(red[0][t]+red[1][t]+red[2][t]+red[3][t] + pgen_b[0]);
    }
}

// ---------------- gen logits: K-chunked register pipeline, fused sm partials --------
#define GEN_SLICE(KS, RA, RB) \
  { short8v bb_; \
    bb_[0]=f2bf(RA[0]); bb_[1]=f2bf(RA[1]); bb_[2]=f2bf(RA[2]); bb_[3]=f2bf(RA[3]); \
    bb_[4]=f2bf(RB[0]); bb_[5]=f2bf(RB[1]); bb_[6]=f2bf(RB[2]); bb_[7]=f2bf(RB[3]); \
    const int cc_ = (KS)*4 + qw; \
    const int cs_ = (cc_ ^ (lr&7))<<3; \
    short8v aa0_ = *(const short8v*)&As[(lr     )*256 + cs_]; \
    short8v aa1_ = *(const short8v*)&As[(16+lr)*256 + cs_]; \
    short8v aa2_ = *(const short8v*)&As[(32+lr)*256 + cs_]; \
    short8v aa3_ = *(const short8v*)&As[(48+lr)*256 + cs_]; \
    acc0 = __builtin_amdgcn_mfma_f32_16x16x32_bf16(aa0_, bb_, acc0, 0,0,0); \
    acc1 = __builtin_amdgcn_mfma_f32_16x16x32_bf16(aa1_, bb_, acc1, 0,0,0); \
    acc2 = __builtin_amdgcn_mfma_f32_16x16x32_bf16(aa2_, bb_, acc2, 0,0,0); \
    acc3 = __builtin_amdgcn_mfma_f32_16x16x32_bf16(aa3_, bb_, acc3, 0,0,0); }

__global__ __launch_bounds__(256, 3) void k_gen_mfma(
    const short* __restrict__ pregenb, const float* __restrict__ gen_w,
    const float* __restrict__ gen_b, float* __restrict__ logits,
    float* __restrict__ blkM, float* __restrict__ blkS, int W)
{
    const int blk = blockIdx.x;
    const int v0 = blk * 64;
    const int tid = threadIdx.x;
    const int wave = tid>>6, lane = tid&63, qw = lane>>4, lr = lane&15;

    __shared__ __align__(16) short As[64*256];
    __shared__ float pm[4][64];
    __shared__ float ps[4][64];

    const int vrow = v0 + wave*16 + lr;
    const bool bval = (vrow < VV);
    const f32x4* bq = (const f32x4*)(gen_w + (size_t)(bval ? vrow : 0)*DD + qw*8);
    f32x4 a0 = bq[ 0], a1 = bq[ 1];
    f32x4 a2 = bq[ 8], a3 = bq[ 9];
    f32x4 a4 = bq[16], a5 = bq[17];
    f32x4 a6 = bq[24], a7 = bq[25];

    #pragma unroll
    for (int j=0; j<8; j++){
        int f = tid + j*256;
        int row = f >> 5, c = f & 31;
        short8v s = ((const short8v*)pregenb)[f];
        *(short8v*)&As[row*256 + ((c ^ (row&7))<<3)] = s;
    }
    __syncthreads();

    f32x4 acc0 = f32x4{0.f,0.f,0.f,0.f};
    f32x4 acc1 = f32x4{0.f,0.f,0.f,0.f};
    f32x4 acc2 = f32x4{0.f,0.f,0.f,0.f};
    f32x4 acc3 = f32x4{0.f,0.f,0.f,0.f};

    f32x4 b0 = bq[32], b1 = bq[33];
    f32x4 b2 = bq[40], b3 = bq[41];
    f32x4 b4 = bq[48], b5 = bq[49];
    f32x4 b6 = bq[56], b7 = bq[57];

    GEN_SLICE(0, a0, a1);
    GEN_SLICE(1, a2, a3);
    GEN_SLICE(2, a4, a5);
    GEN_SLICE(3, a6, a7);
    asm volatile("" : "+v"(b0),"+v"(b1),"+v"(b2),"+v"(b3),
                      "+v"(b4),"+v"(b5),"+v"(b6),"+v"(b7));
    GEN_SLICE(4, b0, b1);
    GEN_SLICE(5, b2, b3);
    GEN_SLICE(6, b4, b5);
    GEN_SLICE(7, b6, b7);

    f32x4 accs[4] = {acc0, acc1, acc2, acc3};
    const int v = v0 + wave*16 + lr;
    const bool vv = (v < VV);
    const float gb = vv ? gen_b[v] : 0.f;
    #pragma unroll
    for (int rf=0; rf<4; rf++){
        #pragma unroll
        for (int r=0; r<4; r++){
            float lg = accs[rf][r] + gb;
            int bt = rf*16 + qw*4 + r;
            if (vv) logits[(size_t)bt*W + v] = lg;
            float x = vv ? lg : -1e30f;
            float mx = x;
            mx = fmaxf(mx, __shfl_xor(mx,1));
            mx = fmaxf(mx, __shfl_xor(mx,2));
            mx = fmaxf(mx, __shfl_xor(mx,4));
            mx = fmaxf(mx, __shfl_xor(mx,8));
            float e = vv ? expf(x - mx) : 0.f;
            e += __shfl_xor(e,1); e += __shfl_xor(e,2);
            e += __shfl_xor(e,4); e += __shfl_xor(e,8);
            if (lr == 0){ pm[wave][bt] = mx; ps[wave][bt] = e; }
        }
    }
    __syncthreads();
    if (tid < 64){
        float M = fmaxf(fmaxf(pm[0][tid], pm[1][tid]), fmaxf(pm[2][tid], pm[3][tid]));
        float S = ps[0][tid]*expf(pm[0][tid]-M) + ps[1][tid]*expf(pm[1][tid]-M)
                + ps[2][tid]*expf(pm[2][tid]-M) + ps[3][tid]*expf(pm[3][tid]-M);
        blkM[(size_t)tid*NB + blk] = M;
        blkS[(size_t)tid*NB + blk] = S;
    }
}

// ---------------- reduce per-block partials -> M,S per batch -----------------------
__global__ __launch_bounds__(256) void k_vred(
    const float* __restrict__ blkM, const float* __restrict__ blkS,
    float* __restrict__ Ms, float* __restrict__ Ss)
{
    const int b = blockIdx.x, t = threadIdx.x;
    __shared__ float red[256];
    float m = -INFINITY;
    for (int i=t; i<NB; i+=256) m = fmaxf(m, blkM[(size_t)b*NB + i]);
    red[t]=m; __syncthreads();
    for (int s=128;s>0;s>>=1){ if(t<s) red[t]=fmaxf(red[t],red[t+s]); __syncthreads(); }
    const float M = red[0]; __syncthreads();
    float s = 0.f;
    for (int i=t; i<NB; i+=256) s += blkS[(size_t)b*NB + i] * expf(blkM[(size_t)b*NB + i] - M);
    red[t]=s; __syncthreads();
    for (int st=128;st>0;st>>=1){ if(t<st) red[t]+=red[t+st]; __syncthreads(); }
    if (t==0){ Ms[b]=M; Ss[b]=red[0]; }
}

// ---------------- normalize + zero ext ----------------------------------------------
__global__ void k_final(float* __restrict__ out, const float* __restrict__ Ms,
                        const float* __restrict__ Ss, const float* __restrict__ pgen, int W)
{
    size_t idx = (size_t)blockIdx.x*blockDim.x + threadIdx.x;
    if (idx >= (size_t)BB*W) return;
    int b = (int)(idx / W);
    int v = (int)(idx % W);
    float* row = out + (size_t)b*W;
    if (v < VV) row[v] = pgen[b] * expf(row[v]-Ms[b]) / Ss[b];
    else        row[v] = 0.f;
}

// ---------------- scatter-add copy dist ----------------------------------------------
__global__ void k_scatter(float* __restrict__ out, const int* __restrict__ ext,
                          const float* __restrict__ attn, const float* __restrict__ pgen, int W)
{
    int idx = blockIdx.x*blockDim.x + threadIdx.x;
    if (idx >= BB*LL) return;
    int b = idx / LL;
    atomicAdd(out + (size_t)b*W + ext[idx], (1.0f - pgen[b]) * attn[idx]);
}

extern "C" void kernel_launch(void* const* d_in, const int* in_sizes, int n_in,
                              void* d_out, int out_size, void* d_ws, size_t ws_size,
                              hipStream_t stream)
{
    const int*   inp     = (const int*)  d_in[0];
    const float* hh      = (const float*)d_in[1];
    const float* hc      = (const float*)d_in[2];
    const float* enc     = (const float*)d_in[3];
    const float* prev    = (const float*)d_in[4];
    const int*   ext     = (const int*)  d_in[5];
    const float* cov     = (const float*)d_in[6];
    const float* pmask   = (const float*)d_in[7];
    const int*   step_p  = (const int*)  d_in[9];
    const float* emb_w   = (const float*)d_in[10];
    const float* lin_w   = (const float*)d_in[11];
    const float* lin_b   = (const float*)d_in[12];
    const float* w_ih    = (const float*)d_in[13];
    const float* w_hh    = (const float*)d_in[14];
    const float* b_ih    = (const float*)d_in[15];
    const float* b_hh    = (const float*)d_in[16];
    const float* rhw     = (const float*)d_in[17];
    const float* rhb     = (const float*)d_in[18];
    const float* rcw     = (const float*)d_in[19];
    const float* rcb     = (const float*)d_in[20];
    const float* wq_w    = (const float*)d_in[21];
    const float* wq_b    = (const float*)d_in[22];
    const float* cov_w   = (const float*)d_in[23];
    const float* cov_b   = (const float*)d_in[24];
    const float* wk_w    = (const float*)d_in[25];
    const float* wk_b    = (const float*)d_in[26];
    const float* pre_w   = (const float*)d_in[27];
    const float* pre_b   = (const float*)d_in[28];
    const float* gen_w   = (const float*)d_in[29];
    const float* gen_b   = (const float*)d_in[30];
    const float* pgen_w  = (const float*)d_in[31];
    const float* pgen_b  = (const float*)d_in[32];

    const int W = out_size / BB - 4*DD - 2*LL - 1;  // V + ex_size = 50200
    float* out     = (float*)d_out;
    float* o_final = out;
    float* o_h     = out + (size_t)BB*W;
    float* o_c     = o_h + BB*DD;
    float* o_wc    = o_c + BB*DD;
    float* o_attn  = o_wc + BB*2*DD;
    float* o_cov   = o_attn + BB*LL;
    float* o_pgen  = o_cov + BB*LL;

    // workspace
    float* W_actT   = (float*)d_ws;                  // 1280*64 floats
    float* W_whT    = W_actT + 1280*64;              // B*D
    float* W_wcT0   = W_whT + BB*DD;                 // B*D
    float* W_q      = W_wcT0 + BB*DD;                // B*D
    float* W_score  = W_q + BB*DD;                   // B*L
    float* W_m      = W_score + BB*LL;               // B
    float* W_s      = W_m + BB;                      // B
    float* W_u      = W_s + BB;                      // D
    float* W_v2     = W_u + DD;                      // D
    float* W_blkM   = W_v2 + DD;                     // B*NB
    float* W_blkS   = W_blkM + (size_t)BB*NB;        // B*NB
    short* W_wb     = (short*)(W_blkS + (size_t)BB*NB);  // 64*2048 shorts
    short* W_pgb    = (short*)(W_wb + 64*2048);          // B*D bf16

    hipMemsetAsync(o_wc, 0, (size_t)BB*2*DD*sizeof(float), stream);

    k_front1<<<dim3(DD,4), 256, 0, stream>>>(inp, hh, hc, prev, emb_w, lin_w, lin_b,
                                             rhw, rhb, rcw, rcb, step_p,
                                             wk_w, wk_b, cov_w, cov_b,
                                             W_actT, W_whT, W_wcT0, W_wb, W_u, W_v2);
    k_gl<<<DD, 256, 0, stream>>>(W_actT, W_whT, W_wcT0, w_ih, w_hh, b_ih, b_hh,
                                 o_h, o_c, W_actT);
    k_q2<<<DD, 256, 0, stream>>>(W_actT, wq_w, wq_b, W_q);
    k_score_mfma<<<dim3(13, BB), 1024, 0, stream>>>(enc, W_wb, W_u, W_v2, W_q, cov, pmask, W_score);
    k_wcsm<<<dim3(16, BB), 512, 0, stream>>>(W_score, cov, enc, o_attn, o_cov, o_wc);
    k_tr<<<8, 256, 0, stream>>>(o_wc, W_actT);
    k_pregen<<<DD, 256, 0, stream>>>(W_actT, pre_w, pre_b, pgen_w, pgen_b, W_pgb, o_pgen);
    k_gen_mfma<<<NB, 256, 0, stream>>>(W_pgb, gen_w, gen_b, o_final, W_blkM, W_blkS, W);
    k_vred<<<BB, 256, 0, stream>>>(W_blkM, W_blkS, W_m, W_s);
    k_final<<<(int)(((size_t)BB*W+255)/256), 256, 0, stream>>>(o_final, W_m, W_s, o_pgen, W);
    k_scatter<<<(BB*LL+255)/256, 256, 0, stream>>>(o_final, ext, o_attn, o_pgen, W);
}

// Round 14
// 142.042 us; speedup vs baseline: 1.0040x; 1.0040x over previous
//
#include <hip/hip_runtime.h>
#include <math.h>

// V=50000, E=128, D=256, L=400, B=64
#define BB 64
#define DD 256
#define LL 400
#define VV 50000
#define EE 128
#define NB 782   // ceil(VV/64)

typedef __attribute__((ext_vector_type(8))) short short8v;
typedef __attribute__((ext_vector_type(4))) short short4v;
typedef __attribute__((ext_vector_type(4))) float f32x4;

__device__ __forceinline__ float sigmoidf_(float x){ return 1.0f/(1.0f+expf(-x)); }

__device__ __forceinline__ short f2bf(float f){
    unsigned u = __builtin_bit_cast(unsigned, f);
    u += 0x7fffu + ((u>>16)&1u);
    return (short)(u>>16);
}

// actT layout (transposed activations [row][batch], 64 floats per row):
//   rows    0..255 : x
//   rows  256..767 : weighted context (wc)
//   rows 768..1023 : h_new
//   rows 1024..1279: c_new
#define ROW_X   0
#define ROW_WC  256
#define ROW_H   768
#define ROW_C   1024

// 8 independent column loads + pin + 8 FMAs (keeps 8 loads in flight; the
// compiler otherwise sinks each load to its use -> 1 load in flight, ~500cyc/it)
#define DOT8(col, wptr, kk, acc) { \
    float a0_=(col)[((kk)+0)*64], a1_=(col)[((kk)+1)*64], a2_=(col)[((kk)+2)*64], a3_=(col)[((kk)+3)*64], \
          a4_=(col)[((kk)+4)*64], a5_=(col)[((kk)+5)*64], a6_=(col)[((kk)+6)*64], a7_=(col)[((kk)+7)*64]; \
    asm volatile("" : "+v"(a0_),"+v"(a1_),"+v"(a2_),"+v"(a3_),"+v"(a4_),"+v"(a5_),"+v"(a6_),"+v"(a7_)); \
    acc += a0_*(wptr)[(kk)+0] + a1_*(wptr)[(kk)+1] + a2_*(wptr)[(kk)+2] + a3_*(wptr)[(kk)+3] \
         + a4_*(wptr)[(kk)+4] + a5_*(wptr)[(kk)+5] + a6_*(wptr)[(kk)+6] + a7_*(wptr)[(kk)+7]; }

__device__ __forceinline__ float dot4v(f32x4 a, f32x4 b){
    return a[0]*b[0] + a[1]*b[1] + a[2]*b[2] + a[3]*b[3];
}

// ============ FRONT STAGE 1: x, h, c (+ score prep) ================================
// grid (DD,4) x 256. y0: x -> actT rows 0..255. y1/y2: reduced h/c -> WhT/WcT0.
// y3: Wb fragment-order pack + u,v2.
__global__ __launch_bounds__(256) void k_front1(
    const int* __restrict__ inp, const float* __restrict__ hh, const float* __restrict__ hc,
    const float* __restrict__ prev, const float* __restrict__ emb_w,
    const float* __restrict__ lin_w, const float* __restrict__ lin_b,
    const float* __restrict__ rhw, const float* __restrict__ rhb,
    const float* __restrict__ rcw, const float* __restrict__ rcb,
    const int* __restrict__ step_p,
    const float* __restrict__ wk_w, const float* __restrict__ wk_b,
    const float* __restrict__ cov_w, const float* __restrict__ cov_b,
    float* __restrict__ actT, float* __restrict__ WhT, float* __restrict__ WcT0,
    short* __restrict__ Wb, float* __restrict__ u, float* __restrict__ v2)
{
    const int d = blockIdx.x, y = blockIdx.y, t = threadIdx.x;
    const int b = t >> 2, kq = t & 3;
    __shared__ float lw[640];
    __shared__ float red[256];

    if (y == 3){
        const float* row = wk_w + (size_t)d*512;
        float su=0.f, sv=0.f;
        for (int j=t; j<512; j+=256){
            float wv = row[j];
            Wb[(size_t)(j>>3)*2048 + d*8 + (j&7)] = f2bf(wv);
            su += wv*cov_w[j];
            sv += wv*cov_b[j];
        }
        float* rs = lw;
        float* rv = red;
        rs[t]=su; rv[t]=sv; __syncthreads();
        for (int s=128;s>0;s>>=1){ if(t<s){rs[t]+=rs[t+s]; rv[t]+=rv[t+s];} __syncthreads(); }
        if (t==0){ u[d]=rs[0]; v2[d]=rv[0] + wk_b[d]; }
        return;
    }

    if (y == 0){
        if (t < 160) ((f32x4*)lw)[t] = ((const f32x4*)(lin_w + (size_t)d*640))[t];
        __syncthreads();
        const f32x4* lw4 = (const f32x4*)lw;
        const f32x4* er4 = (const f32x4*)(emb_w + (size_t)inp[b]*EE);
        const f32x4* pv4 = (const f32x4*)(prev + (size_t)b*512);
        float acc = 0.f;
        for (int i=kq; i<160; i+=16){
            f32x4 v0 = (i    < 32) ? er4[i]    : pv4[i-32];
            f32x4 v1 = (i+4  < 32) ? er4[i+4]  : pv4[i-28];
            f32x4 v2_ = pv4[i-24];   // i+8 >= 32 always when i>=24; guard below
            f32x4 v3 = pv4[i-20];
            if (i+8  < 32) v2_ = er4[i+8];
            if (i+12 < 32) v3 = er4[i+12];
            asm volatile("" : "+v"(v0),"+v"(v1),"+v"(v2_),"+v"(v3));
            acc += dot4v(v0, lw4[i]) + dot4v(v1, lw4[i+4])
                 + dot4v(v2_, lw4[i+8]) + dot4v(v3, lw4[i+12]);
        }
        acc += __shfl_xor(acc,1); acc += __shfl_xor(acc,2);
        if (kq == 0) actT[(ROW_X + d)*64 + b] = lin_b[d] + acc;
        return;
    }

    const float* src  = (y==1) ? hh  : hc;
    float*       dstT = (y==1) ? WhT : WcT0;
    if (*step_p == 0){
        const float* wrow = ((y==1) ? rhw : rcw) + (size_t)d*512;
        const float  bias = ((y==1) ? rhb : rcb)[d];
        if (t < 128) ((f32x4*)lw)[t] = ((const f32x4*)wrow)[t];
        __syncthreads();
        const f32x4* lw4 = (const f32x4*)lw;
        const f32x4* s0 = (const f32x4*)(src + (size_t)b*DD);
        const f32x4* s1 = (const f32x4*)(src + (size_t)BB*DD + (size_t)b*DD);
        float acc = 0.f;
        for (int i=kq; i<128; i+=16){
            f32x4 v0 = (i    < 64) ? s0[i]    : s1[i-64];
            f32x4 v1 = (i+4  < 64) ? s0[i+4]  : s1[i-60];
            f32x4 v2_ = (i+8 < 64) ? s0[i+8]  : s1[i-56];
            f32x4 v3 = (i+12 < 64) ? s0[i+12] : s1[i-52];
            asm volatile("" : "+v"(v0),"+v"(v1),"+v"(v2_),"+v"(v3));
            acc += dot4v(v0, lw4[i]) + dot4v(v1, lw4[i+4])
                 + dot4v(v2_, lw4[i+8]) + dot4v(v3, lw4[i+12]);
        }
        acc += __shfl_xor(acc,1); acc += __shfl_xor(acc,2);
        if (kq == 0){
            float a = bias + acc;
            dstT[d*64 + b] = a>0.f ? a : 0.f;
        }
    } else {
        if (t < 64) dstT[d*64 + t] = src[(size_t)t*DD + d];
    }
}

// ============ FRONT STAGE 2: gates + LSTM (8-deep load groups) ======================
__global__ __launch_bounds__(256) void k_gl(
    const float* __restrict__ actT, const float* __restrict__ WhT, const float* __restrict__ WcT0,
    const float* __restrict__ w_ih, const float* __restrict__ w_hh,
    const float* __restrict__ b_ih, const float* __restrict__ b_hh,
    float* __restrict__ o_h, float* __restrict__ o_c, float* __restrict__ actT_out)
{
    const int d = blockIdx.x, t = threadIdx.x;
    const int b = t & 63, gi = t >> 6;
    __shared__ float wih[4][256];
    __shared__ float whh[4][256];
    __shared__ float gl[4][64];

    const int gr = gi*DD + d;
    ((f32x4*)&wih[gi][0])[b] = ((const f32x4*)(w_ih + (size_t)gr*DD))[b];
    ((f32x4*)&whh[gi][0])[b] = ((const f32x4*)(w_hh + (size_t)gr*DD))[b];
    __syncthreads();

    const float* xcol = actT + ROW_X*64 + b;
    const float* hcol = WhT + b;
    float a0=0.f, a1=0.f;
    for (int kk=0; kk<256; kk+=8){
        DOT8(xcol, &wih[gi][0], kk, a0);
        DOT8(hcol, &whh[gi][0], kk, a1);
    }
    gl[gi][b] = a0 + a1 + b_ih[gr] + b_hh[gr];
    __syncthreads();

    if (t < 64){
        float iv = sigmoidf_(gl[0][t]);
        float fv = sigmoidf_(gl[1][t]);
        float gv = tanhf(gl[2][t]);
        float ov = sigmoidf_(gl[3][t]);
        float cn = fv*WcT0[d*64 + t] + iv*gv;
        float hn = ov*tanhf(cn);
        o_c[(size_t)t*DD + d] = cn;
        o_h[(size_t)t*DD + d] = hn;
        actT_out[(ROW_C + d)*64 + t] = cn;
        actT_out[(ROW_H + d)*64 + t] = hn;
    }
}

// ============ FRONT STAGE 3: Q (8-deep load groups over actT h/c rows) =============
__global__ __launch_bounds__(256) void k_q2(
    const float* __restrict__ actT,
    const float* __restrict__ wq_w, const float* __restrict__ wq_b,
    float* __restrict__ Qs)
{
    const int d = blockIdx.x, t = threadIdx.x;
    const int b = t & 63, w = t >> 6;
    __shared__ float lw[512];
    __shared__ float red[4][64];
    if (t < 128) ((f32x4*)lw)[t] = ((const f32x4*)(wq_w + (size_t)d*512))[t];
    __syncthreads();
    const float* col = actT + ROW_H*64 + b;   // rows 768..1279 = [h(256), c(256)]
    float acc = 0.f;
    const int k0 = w*128;
    for (int kk=k0; kk<k0+128; kk+=8)
        DOT8(col, lw, kk, acc);
    red[w][b] = acc; __syncthreads();
    if (t < 64)
        Qs[(size_t)t*DD + d] = tanhf(wq_b[d] + red[0][t]+red[1][t]+red[2][t]+red[3][t]) * 0.0625f;
}

// ---------------- score: MFMA bf16, K-chunked reg pipeline, packed-B ----------------
#define SC_MFMA(KS, BF) \
  { const int cc_ = (KS)*4 + qw; \
    short8v a0_ = *(const short8v*)&As[lr*512 + ((cc_ ^ (lr&7))<<3)]; \
    short8v a1_ = *(const short8v*)&As[(16+lr)*512 + ((cc_ ^ (lr&7))<<3)]; \
    acc0 = __builtin_amdgcn_mfma_f32_16x16x32_bf16(a0_, BF, acc0, 0,0,0); \
    acc1 = __builtin_amdgcn_mfma_f32_16x16x32_bf16(a1_, BF, acc1, 0,0,0); }

#define SC_CHUNK(KC, B0,B1,B2,B3) \
    SC_MFMA((KC)*4+0, B0); SC_MFMA((KC)*4+1, B1); \
    SC_MFMA((KC)*4+2, B2); SC_MFMA((KC)*4+3, B3);

__global__ __launch_bounds__(1024, 4) void k_score_mfma(
    const float* __restrict__ enc, const short* __restrict__ Wb,
    const float* __restrict__ u, const float* __restrict__ v2,
    const float* __restrict__ Qs, const float* __restrict__ cov,
    const float* __restrict__ pmask, float* __restrict__ score)
{
    const int b  = blockIdx.y;
    const int l0 = blockIdx.x * 32;
    const int tid = threadIdx.x;
    const int wave = tid >> 6, lane = tid & 63;
    const int qw = lane >> 4, lr = lane & 15;
    const int col = wave*16 + lr;

    __shared__ __align__(16) short As[32*512];
    __shared__ float Red[16][32];

    const short* bp = Wb + (size_t)qw*2048 + col*8;
    short8v c0 = *(const short8v*)(bp +  0*8192);
    short8v c1 = *(const short8v*)(bp +  1*8192);
    short8v c2 = *(const short8v*)(bp +  2*8192);
    short8v c3 = *(const short8v*)(bp +  3*8192);

    const int arow = tid >> 5;
    const int af   = tid & 31;
    const bool aval = (l0 + arow) < LL;
    const float4* aptr = (const float4*)(enc + ((size_t)(b*LL + (aval ? l0+arow : 0)))*512);
    float4 areg[4];
    #pragma unroll
    for (int j=0; j<4; j++)
        areg[j] = aval ? aptr[af + j*32] : float4{0.f,0.f,0.f,0.f};

    #pragma unroll
    for (int j=0; j<4; j++){
        const int fi   = af + j*32;
        const int c    = fi >> 1;
        const int half = fi & 1;
        const int cs   = c ^ (arow & 7);
        short4v t4;
        t4[0]=f2bf(areg[j].x); t4[1]=f2bf(areg[j].y);
        t4[2]=f2bf(areg[j].z); t4[3]=f2bf(areg[j].w);
        *(short4v*)&As[arow*512 + cs*8 + half*4] = t4;
    }
    __syncthreads();

    f32x4 acc0 = f32x4{0.f,0.f,0.f,0.f};
    f32x4 acc1 = f32x4{0.f,0.f,0.f,0.f};

    short8v n0 = *(const short8v*)(bp +  4*8192);
    short8v n1 = *(const short8v*)(bp +  5*8192);
    short8v n2 = *(const short8v*)(bp +  6*8192);
    short8v n3 = *(const short8v*)(bp +  7*8192);
    SC_CHUNK(0, c0,c1,c2,c3);
    asm volatile("" : "+v"(n0),"+v"(n1),"+v"(n2),"+v"(n3));

    c0 = *(const short8v*)(bp +  8*8192);
    c1 = *(const short8v*)(bp +  9*8192);
    c2 = *(const short8v*)(bp + 10*8192);
    c3 = *(const short8v*)(bp + 11*8192);
    SC_CHUNK(1, n0,n1,n2,n3);
    asm volatile("" : "+v"(c0),"+v"(c1),"+v"(c2),"+v"(c3));

    n0 = *(const short8v*)(bp + 12*8192);
    n1 = *(const short8v*)(bp + 13*8192);
    n2 = *(const short8v*)(bp + 14*8192);
    n3 = *(const short8v*)(bp + 15*8192);
    SC_CHUNK(2, c0,c1,c2,c3);
    asm volatile("" : "+v"(n0),"+v"(n1),"+v"(n2),"+v"(n3));

    SC_CHUNK(3, n0,n1,n2,n3);

    const float qv = Qs[b*DD + col];
    const float uv = u[col];
    const float vv = v2[col];
    #pragma unroll
    for (int rf=0; rf<2; rf++){
        const f32x4 acc = rf ? acc1 : acc0;
        const int rbase = l0 + rf*16 + qw*4;
        float cv[4];
        if (rbase < LL){
            float4 c4v = *(const float4*)(cov + (size_t)b*LL + rbase);
            cv[0]=c4v.x; cv[1]=c4v.y; cv[2]=c4v.z; cv[3]=c4v.w;
        } else { cv[0]=cv[1]=cv[2]=cv[3]=0.f; }
        #pragma unroll
        for (int r=0; r<4; r++){
            float s = qv * tanhf(acc[r] + cv[r]*uv + vv);
            s += __shfl_xor(s,1); s += __shfl_xor(s,2);
            s += __shfl_xor(s,4); s += __shfl_xor(s,8);
            if (lr == 0) Red[wave][rf*16 + qw*4 + r] = s;
        }
    }
    __syncthreads();
    if (tid < 32){
        int l = l0 + tid;
        if (l < LL){
            float s = 0.f;
            #pragma unroll
            for (int w2=0; w2<16; w2++) s += Red[w2][tid];
            score[b*LL + l] = (pmask[b*LL+l] > 0.f) ? s : -1e18f;
        }
    }
}

// ---------------- fused softmax(L) + weighted context ------------------------------
__global__ __launch_bounds__(512) void k_wcsm(
    const float* __restrict__ score, const float* __restrict__ cov_in,
    const float* __restrict__ enc,
    float* __restrict__ attn_out, float* __restrict__ cov_out, float* __restrict__ wc)
{
    const int b = blockIdx.y, ch = blockIdx.x;
    const int t = threadIdx.x;
    __shared__ float sc[LL];
    __shared__ float red[512];

    float v = (t < LL) ? score[b*LL + t] : -INFINITY;
    red[t] = v; __syncthreads();
    for (int s=256;s>0;s>>=1){ if(t<s) red[t]=fmaxf(red[t],red[t+s]); __syncthreads(); }
    float m = red[0]; __syncthreads();
    float e = (t < LL) ? expf(v - m) : 0.f;
    if (t < LL) sc[t] = e;
    red[t] = e; __syncthreads();
    for (int s=256;s>0;s>>=1){ if(t<s) red[t]+=red[t+s]; __syncthreads(); }
    const float inv = 1.0f / red[0];

    const int l0 = ch * (LL/16);
    float s = 0.f;
    #pragma unroll 5
    for (int l=l0; l<l0+LL/16; ++l)
        s += sc[l] * enc[((size_t)(b*LL+l))*512 + t];
    atomicAdd(&wc[b*512 + t], s * inv);

    if (ch == 0 && t < LL){
        attn_out[b*LL + t] = sc[t] * inv;
        cov_out[b*LL + t]  = cov_in[b*LL + t];
    }
}

// ---------------- transpose wc -> actT rows 256..767 (LDS tile) --------------------
__global__ __launch_bounds__(256) void k_tr(const float* __restrict__ wc,
                                            float* __restrict__ actT)
{
    const int j0 = blockIdx.x * 64;   // 8 blocks cover 512 j's
    __shared__ float tile[64][65];
    const int t = threadIdx.x;
    const int c = t & 63, r0 = t >> 6;
    #pragma unroll
    for (int bb = r0; bb < 64; bb += 4)
        tile[bb][c] = wc[(size_t)bb*512 + j0 + c];
    __syncthreads();
    #pragma unroll
    for (int jj = r0; jj < 64; jj += 4)
        actT[(ROW_WC + j0 + jj)*64 + c] = tile[c][jj];
}

// ============ pregen (+ p_gen in block 0), 8-deep load groups ======================
__global__ __launch_bounds__(256) void k_pregen(
    const float* __restrict__ actT,
    const float* __restrict__ pre_w, const float* __restrict__ pre_b,
    const float* __restrict__ pgen_w, const float* __restrict__ pgen_b,
    short* __restrict__ pregenb, float* __restrict__ pgen_out)
{
    const int d = blockIdx.x, t = threadIdx.x;
    const int b = t & 63, w = t >> 6;
    __shared__ float pw[768];
    __shared__ float red[4][64];
    if (t < 192) ((f32x4*)pw)[t] = ((const f32x4*)(pre_w + (size_t)d*768))[t];
    __syncthreads();
    // pre dot: rows 256..1023 = [wc(512), h(256)] contiguous
    const float* col = actT + ROW_WC*64 + b;
    float acc = 0.f;
    const int k0 = w*192;
    for (int kk=k0; kk<k0+192; kk+=8)
        DOT8(col, pw, kk, acc);
    red[w][b] = acc; __syncthreads();
    if (t < 64)
        pregenb[(size_t)t*DD + d] = f2bf(pre_b[d] + red[0][t]+red[1][t]+red[2][t]+red[3][t]);

    if (blockIdx.x == 0){
        __syncthreads();
        // p_gen: rows 0..1279 = [x, wc, h, c] — matches pgen_w order
        const float* colx = actT + b;
        float p = 0.f;
        const int j0 = w*320;
        for (int jj=j0; jj<j0+320; jj+=8)
            DOT8(colx, pgen_w, jj, p);
        red[w][b] = p; __syncthreads();
        if (t < 64)
            pgen_out[t] = sigmoidf_(red[0][t]+red[1][t]+red[2][t]+red[3][t] + pgen_b[0]);
    }
}

// ---------------- gen logits: K-chunked register pipeline, fused sm partials --------
#define GEN_SLICE(KS, RA, RB) \
  { short8v bb_; \
    bb_[0]=f2bf(RA[0]); bb_[1]=f2bf(RA[1]); bb_[2]=f2bf(RA[2]); bb_[3]=f2bf(RA[3]); \
    bb_[4]=f2bf(RB[0]); bb_[5]=f2bf(RB[1]); bb_[6]=f2bf(RB[2]); bb_[7]=f2bf(RB[3]); \
    const int cc_ = (KS)*4 + qw; \
    const int cs_ = (cc_ ^ (lr&7))<<3; \
    short8v aa0_ = *(const short8v*)&As[(lr     )*256 + cs_]; \
    short8v aa1_ = *(const short8v*)&As[(16+lr)*256 + cs_]; \
    short8v aa2_ = *(const short8v*)&As[(32+lr)*256 + cs_]; \
    short8v aa3_ = *(const short8v*)&As[(48+lr)*256 + cs_]; \
    acc0 = __builtin_amdgcn_mfma_f32_16x16x32_bf16(aa0_, bb_, acc0, 0,0,0); \
    acc1 = __builtin_amdgcn_mfma_f32_16x16x32_bf16(aa1_, bb_, acc1, 0,0,0); \
    acc2 = __builtin_amdgcn_mfma_f32_16x16x32_bf16(aa2_, bb_, acc2, 0,0,0); \
    acc3 = __builtin_amdgcn_mfma_f32_16x16x32_bf16(aa3_, bb_, acc3, 0,0,0); }

__global__ __launch_bounds__(256, 3) void k_gen_mfma(
    const short* __restrict__ pregenb, const float* __restrict__ gen_w,
    const float* __restrict__ gen_b, float* __restrict__ logits,
    float* __restrict__ blkM, float* __restrict__ blkS, int W)
{
    const int blk = blockIdx.x;
    const int v0 = blk * 64;
    const int tid = threadIdx.x;
    const int wave = tid>>6, lane = tid&63, qw = lane>>4, lr = lane&15;

    __shared__ __align__(16) short As[64*256];
    __shared__ float pm[4][64];
    __shared__ float ps[4][64];

    const int vrow = v0 + wave*16 + lr;
    const bool bval = (vrow < VV);
    const f32x4* bq = (const f32x4*)(gen_w + (size_t)(bval ? vrow : 0)*DD + qw*8);
    f32x4 a0 = bq[ 0], a1 = bq[ 1];
    f32x4 a2 = bq[ 8], a3 = bq[ 9];
    f32x4 a4 = bq[16], a5 = bq[17];
    f32x4 a6 = bq[24], a7 = bq[25];

    #pragma unroll
    for (int j=0; j<8; j++){
        int f = tid + j*256;
        int row = f >> 5, c = f & 31;
        short8v s = ((const short8v*)pregenb)[f];
        *(short8v*)&As[row*256 + ((c ^ (row&7))<<3)] = s;
    }
    __syncthreads();

    f32x4 acc0 = f32x4{0.f,0.f,0.f,0.f};
    f32x4 acc1 = f32x4{0.f,0.f,0.f,0.f};
    f32x4 acc2 = f32x4{0.f,0.f,0.f,0.f};
    f32x4 acc3 = f32x4{0.f,0.f,0.f,0.f};

    f32x4 b0 = bq[32], b1 = bq[33];
    f32x4 b2 = bq[40], b3 = bq[41];
    f32x4 b4 = bq[48], b5 = bq[49];
    f32x4 b6 = bq[56], b7 = bq[57];

    GEN_SLICE(0, a0, a1);
    GEN_SLICE(1, a2, a3);
    GEN_SLICE(2, a4, a5);
    GEN_SLICE(3, a6, a7);
    asm volatile("" : "+v"(b0),"+v"(b1),"+v"(b2),"+v"(b3),
                      "+v"(b4),"+v"(b5),"+v"(b6),"+v"(b7));
    GEN_SLICE(4, b0, b1);
    GEN_SLICE(5, b2, b3);
    GEN_SLICE(6, b4, b5);
    GEN_SLICE(7, b6, b7);

    f32x4 accs[4] = {acc0, acc1, acc2, acc3};
    const int v = v0 + wave*16 + lr;
    const bool vv = (v < VV);
    const float gb = vv ? gen_b[v] : 0.f;
    #pragma unroll
    for (int rf=0; rf<4; rf++){
        #pragma unroll
        for (int r=0; r<4; r++){
            float lg = accs[rf][r] + gb;
            int bt = rf*16 + qw*4 + r;
            if (vv) logits[(size_t)bt*W + v] = lg;
            float x = vv ? lg : -1e30f;
            float mx = x;
            mx = fmaxf(mx, __shfl_xor(mx,1));
            mx = fmaxf(mx, __shfl_xor(mx,2));
            mx = fmaxf(mx, __shfl_xor(mx,4));
            mx = fmaxf(mx, __shfl_xor(mx,8));
            float e = vv ? expf(x - mx) : 0.f;
            e += __shfl_xor(e,1); e += __shfl_xor(e,2);
            e += __shfl_xor(e,4); e += __shfl_xor(e,8);
            if (lr == 0){ pm[wave][bt] = mx; ps[wave][bt] = e; }
        }
    }
    __syncthreads();
    if (tid < 64){
        float M = fmaxf(fmaxf(pm[0][tid], pm[1][tid]), fmaxf(pm[2][tid], pm[3][tid]));
        float S = ps[0][tid]*expf(pm[0][tid]-M) + ps[1][tid]*expf(pm[1][tid]-M)
                + ps[2][tid]*expf(pm[2][tid]-M) + ps[3][tid]*expf(pm[3][tid]-M);
        blkM[(size_t)tid*NB + blk] = M;
        blkS[(size_t)tid*NB + blk] = S;
    }
}

// ---------------- reduce per-block partials -> M,S per batch -----------------------
__global__ __launch_bounds__(256) void k_vred(
    const float* __restrict__ blkM, const float* __restrict__ blkS,
    float* __restrict__ Ms, float* __restrict__ Ss)
{
    const int b = blockIdx.x, t = threadIdx.x;
    __shared__ float red[256];
    float m = -INFINITY;
    for (int i=t; i<NB; i+=256) m = fmaxf(m, blkM[(size_t)b*NB + i]);
    red[t]=m; __syncthreads();
    for (int s=128;s>0;s>>=1){ if(t<s) red[t]=fmaxf(red[t],red[t+s]); __syncthreads(); }
    const float M = red[0]; __syncthreads();
    float s = 0.f;
    for (int i=t; i<NB; i+=256) s += blkS[(size_t)b*NB + i] * expf(blkM[(size_t)b*NB + i] - M);
    red[t]=s; __syncthreads();
    for (int st=128;st>0;st>>=1){ if(t<st) red[t]+=red[t+st]; __syncthreads(); }
    if (t==0){ Ms[b]=M; Ss[b]=red[0]; }
}

// ---------------- normalize + zero ext ----------------------------------------------
__global__ void k_final(float* __restrict__ out, const float* __restrict__ Ms,
                        const float* __restrict__ Ss, const float* __restrict__ pgen, int W)
{
    size_t idx = (size_t)blockIdx.x*blockDim.x + threadIdx.x;
    if (idx >= (size_t)BB*W) return;
    int b = (int)(idx / W);
    int v = (int)(idx % W);
    float* row = out + (size_t)b*W;
    if (v < VV) row[v] = pgen[b] * expf(row[v]-Ms[b]) / Ss[b];
    else        row[v] = 0.f;
}

// ---------------- scatter-add copy dist ----------------------------------------------
__global__ void k_scatter(float* __restrict__ out, const int* __restrict__ ext,
                          const float* __restrict__ attn, const float* __restrict__ pgen, int W)
{
    int idx = blockIdx.x*blockDim.x + threadIdx.x;
    if (idx >= BB*LL) return;
    int b = idx / LL;
    atomicAdd(out + (size_t)b*W + ext[idx], (1.0f - pgen[b]) * attn[idx]);
}

extern "C" void kernel_launch(void* const* d_in, const int* in_sizes, int n_in,
                              void* d_out, int out_size, void* d_ws, size_t ws_size,
                              hipStream_t stream)
{
    const int*   inp     = (const int*)  d_in[0];
    const float* hh      = (const float*)d_in[1];
    const float* hc      = (const float*)d_in[2];
    const float* enc     = (const float*)d_in[3];
    const float* prev    = (const float*)d_in[4];
    const int*   ext     = (const int*)  d_in[5];
    const float* cov     = (const float*)d_in[6];
    const float* pmask   = (const float*)d_in[7];
    const int*   step_p  = (const int*)  d_in[9];
    const float* emb_w   = (const float*)d_in[10];
    const float* lin_w   = (const float*)d_in[11];
    const float* lin_b   = (const float*)d_in[12];
    const float* w_ih    = (const float*)d_in[13];
    const float* w_hh    = (const float*)d_in[14];
    const float* b_ih    = (const float*)d_in[15];
    const float* b_hh    = (const float*)d_in[16];
    const float* rhw     = (const float*)d_in[17];
    const float* rhb     = (const float*)d_in[18];
    const float* rcw     = (const float*)d_in[19];
    const float* rcb     = (const float*)d_in[20];
    const float* wq_w    = (const float*)d_in[21];
    const float* wq_b    = (const float*)d_in[22];
    const float* cov_w   = (const float*)d_in[23];
    const float* cov_b   = (const float*)d_in[24];
    const float* wk_w    = (const float*)d_in[25];
    const float* wk_b    = (const float*)d_in[26];
    const float* pre_w   = (const float*)d_in[27];
    const float* pre_b   = (const float*)d_in[28];
    const float* gen_w   = (const float*)d_in[29];
    const float* gen_b   = (const float*)d_in[30];
    const float* pgen_w  = (const float*)d_in[31];
    const float* pgen_b  = (const float*)d_in[32];

    const int W = out_size / BB - 4*DD - 2*LL - 1;  // V + ex_size = 50200
    float* out     = (float*)d_out;
    float* o_final = out;
    float* o_h     = out + (size_t)BB*W;
    float* o_c     = o_h + BB*DD;
    float* o_wc    = o_c + BB*DD;
    float* o_attn  = o_wc + BB*2*DD;
    float* o_cov   = o_attn + BB*LL;
    float* o_pgen  = o_cov + BB*LL;

    // workspace
    float* W_actT   = (float*)d_ws;                  // 1280*64 floats
    float* W_whT    = W_actT + 1280*64;              // B*D
    float* W_wcT0   = W_whT + BB*DD;                 // B*D
    float* W_q      = W_wcT0 + BB*DD;                // B*D
    float* W_score  = W_q + BB*DD;                   // B*L
    float* W_m      = W_score + BB*LL;               // B
    float* W_s      = W_m + BB;                      // B
    float* W_u      = W_s + BB;                      // D
    float* W_v2     = W_u + DD;                      // D
    float* W_blkM   = W_v2 + DD;                     // B*NB
    float* W_blkS   = W_blkM + (size_t)BB*NB;        // B*NB
    short* W_wb     = (short*)(W_blkS + (size_t)BB*NB);  // 64*2048 shorts
    short* W_pgb    = (short*)(W_wb + 64*2048);          // B*D bf16

    hipMemsetAsync(o_wc, 0, (size_t)BB*2*DD*sizeof(float), stream);

    k_front1<<<dim3(DD,4), 256, 0, stream>>>(inp, hh, hc, prev, emb_w, lin_w, lin_b,
                                             rhw, rhb, rcw, rcb, step_p,
                                             wk_w, wk_b, cov_w, cov_b,
                                             W_actT, W_whT, W_wcT0, W_wb, W_u, W_v2);
    k_gl<<<DD, 256, 0, stream>>>(W_actT, W_whT, W_wcT0, w_ih, w_hh, b_ih, b_hh,
                                 o_h, o_c, W_actT);
    k_q2<<<DD, 256, 0, stream>>>(W_actT, wq_w, wq_b, W_q);
    k_score_mfma<<<dim3(13, BB), 1024, 0, stream>>>(enc, W_wb, W_u, W_v2, W_q, cov, pmask, W_score);
    k_wcsm<<<dim3(16, BB), 512, 0, stream>>>(W_score, cov, enc, o_attn, o_cov, o_wc);
    k_tr<<<8, 256, 0, stream>>>(o_wc, W_actT);
    k_pregen<<<DD, 256, 0, stream>>>(W_actT, pre_w, pre_b, pgen_w, pgen_b, W_pgb, o_pgen);
    k_gen_mfma<<<NB, 256, 0, stream>>>(W_pgb, gen_w, gen_b, o_final, W_blkM, W_blkS, W);
    k_vred<<<BB, 256, 0, stream>>>(W_blkM, W_blkS, W_m, W_s);
    k_final<<<(int)(((size_t)BB*W+255)/256), 256, 0, stream>>>(o_final, W_m, W_s, o_pgen, W);
    k_scatter<<<(BB*LL+255)/256, 256, 0, stream>>>(o_final, ext, o_attn, o_pgen, W);
}

// Round 15
// 138.306 us; speedup vs baseline: 1.0311x; 1.0270x over previous
//
#include <hip/hip_runtime.h>
#include <math.h>

// V=50000, E=128, D=256, L=400, B=64
#define BB 64
#define DD 256
#define LL 400
#define VV 50000
#define EE 128
#define NB 782   // ceil(VV/64)

typedef __attribute__((ext_vector_type(8))) short short8v;
typedef __attribute__((ext_vector_type(4))) short short4v;
typedef __attribute__((ext_vector_type(4))) float f32x4;

__device__ __forceinline__ float sigmoidf_(float x){ return 1.0f/(1.0f+expf(-x)); }

__device__ __forceinline__ short f2bf(float f){
    unsigned u = __builtin_bit_cast(unsigned, f);
    u += 0x7fffu + ((u>>16)&1u);
    return (short)(u>>16);
}

// actT layout (transposed activations [row][batch], 64 floats per row):
//   rows    0..255 : x
//   rows  256..767 : weighted context (wc)
//   rows 768..1023 : h_new
//   rows 1024..1279: c_new
#define ROW_X   0
#define ROW_WC  256
#define ROW_H   768
#define ROW_C   1024

// 8 independent column loads + pin + 8 FMAs (keeps 8 loads in flight)
#define DOT8(col, wptr, kk, acc) { \
    float a0_=(col)[((kk)+0)*64], a1_=(col)[((kk)+1)*64], a2_=(col)[((kk)+2)*64], a3_=(col)[((kk)+3)*64], \
          a4_=(col)[((kk)+4)*64], a5_=(col)[((kk)+5)*64], a6_=(col)[((kk)+6)*64], a7_=(col)[((kk)+7)*64]; \
    asm volatile("" : "+v"(a0_),"+v"(a1_),"+v"(a2_),"+v"(a3_),"+v"(a4_),"+v"(a5_),"+v"(a6_),"+v"(a7_)); \
    acc += a0_*(wptr)[(kk)+0] + a1_*(wptr)[(kk)+1] + a2_*(wptr)[(kk)+2] + a3_*(wptr)[(kk)+3] \
         + a4_*(wptr)[(kk)+4] + a5_*(wptr)[(kk)+5] + a6_*(wptr)[(kk)+6] + a7_*(wptr)[(kk)+7]; }

__device__ __forceinline__ float dot4v(f32x4 a, f32x4 b){
    return a[0]*b[0] + a[1]*b[1] + a[2]*b[2] + a[3]*b[3];
}

// ============ FRONT STAGE 1: x, h, c (+ score prep, + o_wc zeroing) ================
__global__ __launch_bounds__(256) void k_front1(
    const int* __restrict__ inp, const float* __restrict__ hh, const float* __restrict__ hc,
    const float* __restrict__ prev, const float* __restrict__ emb_w,
    const float* __restrict__ lin_w, const float* __restrict__ lin_b,
    const float* __restrict__ rhw, const float* __restrict__ rhb,
    const float* __restrict__ rcw, const float* __restrict__ rcb,
    const int* __restrict__ step_p,
    const float* __restrict__ wk_w, const float* __restrict__ wk_b,
    const float* __restrict__ cov_w, const float* __restrict__ cov_b,
    float* __restrict__ actT, float* __restrict__ WhT, float* __restrict__ WcT0,
    short* __restrict__ Wb, float* __restrict__ u, float* __restrict__ v2,
    float* __restrict__ o_wc)
{
    const int d = blockIdx.x, y = blockIdx.y, t = threadIdx.x;
    const int b = t >> 2, kq = t & 3;
    __shared__ float lw[640];
    __shared__ float red[256];

    if (y == 3){
        // zero o_wc (replaces a 40us fillBufferAligned dispatch)
        if (t < 128) o_wc[d*128 + t] = 0.f;
        const float* row = wk_w + (size_t)d*512;
        float su=0.f, sv=0.f;
        for (int j=t; j<512; j+=256){
            float wv = row[j];
            Wb[(size_t)(j>>3)*2048 + d*8 + (j&7)] = f2bf(wv);
            su += wv*cov_w[j];
            sv += wv*cov_b[j];
        }
        float* rs = lw;
        float* rv = red;
        rs[t]=su; rv[t]=sv; __syncthreads();
        for (int s=128;s>0;s>>=1){ if(t<s){rs[t]+=rs[t+s]; rv[t]+=rv[t+s];} __syncthreads(); }
        if (t==0){ u[d]=rs[0]; v2[d]=rv[0] + wk_b[d]; }
        return;
    }

    if (y == 0){
        if (t < 160) ((f32x4*)lw)[t] = ((const f32x4*)(lin_w + (size_t)d*640))[t];
        __syncthreads();
        const f32x4* lw4 = (const f32x4*)lw;
        const f32x4* er4 = (const f32x4*)(emb_w + (size_t)inp[b]*EE);
        const f32x4* pv4 = (const f32x4*)(prev + (size_t)b*512);
        float acc = 0.f;
        for (int i=kq; i<160; i+=16){
            f32x4 v0 = (i    < 32) ? er4[i]    : pv4[i-32];
            f32x4 v1 = (i+4  < 32) ? er4[i+4]  : pv4[i-28];
            f32x4 v2_ = pv4[i-24];
            f32x4 v3 = pv4[i-20];
            if (i+8  < 32) v2_ = er4[i+8];
            if (i+12 < 32) v3 = er4[i+12];
            asm volatile("" : "+v"(v0),"+v"(v1),"+v"(v2_),"+v"(v3));
            acc += dot4v(v0, lw4[i]) + dot4v(v1, lw4[i+4])
                 + dot4v(v2_, lw4[i+8]) + dot4v(v3, lw4[i+12]);
        }
        acc += __shfl_xor(acc,1); acc += __shfl_xor(acc,2);
        if (kq == 0) actT[(ROW_X + d)*64 + b] = lin_b[d] + acc;
        return;
    }

    const float* src  = (y==1) ? hh  : hc;
    float*       dstT = (y==1) ? WhT : WcT0;
    if (*step_p == 0){
        const float* wrow = ((y==1) ? rhw : rcw) + (size_t)d*512;
        const float  bias = ((y==1) ? rhb : rcb)[d];
        if (t < 128) ((f32x4*)lw)[t] = ((const f32x4*)wrow)[t];
        __syncthreads();
        const f32x4* lw4 = (const f32x4*)lw;
        const f32x4* s0 = (const f32x4*)(src + (size_t)b*DD);
        const f32x4* s1 = (const f32x4*)(src + (size_t)BB*DD + (size_t)b*DD);
        float acc = 0.f;
        for (int i=kq; i<128; i+=16){
            f32x4 v0 = (i    < 64) ? s0[i]    : s1[i-64];
            f32x4 v1 = (i+4  < 64) ? s0[i+4]  : s1[i-60];
            f32x4 v2_ = (i+8 < 64) ? s0[i+8]  : s1[i-56];
            f32x4 v3 = (i+12 < 64) ? s0[i+12] : s1[i-52];
            asm volatile("" : "+v"(v0),"+v"(v1),"+v"(v2_),"+v"(v3));
            acc += dot4v(v0, lw4[i]) + dot4v(v1, lw4[i+4])
                 + dot4v(v2_, lw4[i+8]) + dot4v(v3, lw4[i+12]);
        }
        acc += __shfl_xor(acc,1); acc += __shfl_xor(acc,2);
        if (kq == 0){
            float a = bias + acc;
            dstT[d*64 + b] = a>0.f ? a : 0.f;
        }
    } else {
        if (t < 64) dstT[d*64 + t] = src[(size_t)t*DD + d];
    }
}

// ============ FRONT STAGE 2: gates + LSTM (8-deep load groups) ======================
__global__ __launch_bounds__(256) void k_gl(
    const float* __restrict__ actT, const float* __restrict__ WhT, const float* __restrict__ WcT0,
    const float* __restrict__ w_ih, const float* __restrict__ w_hh,
    const float* __restrict__ b_ih, const float* __restrict__ b_hh,
    float* __restrict__ o_h, float* __restrict__ o_c, float* __restrict__ actT_out)
{
    const int d = blockIdx.x, t = threadIdx.x;
    const int b = t & 63, gi = t >> 6;
    __shared__ float wih[4][256];
    __shared__ float whh[4][256];
    __shared__ float gl[4][64];

    const int gr = gi*DD + d;
    ((f32x4*)&wih[gi][0])[b] = ((const f32x4*)(w_ih + (size_t)gr*DD))[b];
    ((f32x4*)&whh[gi][0])[b] = ((const f32x4*)(w_hh + (size_t)gr*DD))[b];
    __syncthreads();

    const float* xcol = actT + ROW_X*64 + b;
    const float* hcol = WhT + b;
    float a0=0.f, a1=0.f;
    for (int kk=0; kk<256; kk+=8){
        DOT8(xcol, &wih[gi][0], kk, a0);
        DOT8(hcol, &whh[gi][0], kk, a1);
    }
    gl[gi][b] = a0 + a1 + b_ih[gr] + b_hh[gr];
    __syncthreads();

    if (t < 64){
        float iv = sigmoidf_(gl[0][t]);
        float fv = sigmoidf_(gl[1][t]);
        float gv = tanhf(gl[2][t]);
        float ov = sigmoidf_(gl[3][t]);
        float cn = fv*WcT0[d*64 + t] + iv*gv;
        float hn = ov*tanhf(cn);
        o_c[(size_t)t*DD + d] = cn;
        o_h[(size_t)t*DD + d] = hn;
        actT_out[(ROW_C + d)*64 + t] = cn;
        actT_out[(ROW_H + d)*64 + t] = hn;
    }
}

// ============ FRONT STAGE 3: Q =====================================================
__global__ __launch_bounds__(256) void k_q2(
    const float* __restrict__ actT,
    const float* __restrict__ wq_w, const float* __restrict__ wq_b,
    float* __restrict__ Qs)
{
    const int d = blockIdx.x, t = threadIdx.x;
    const int b = t & 63, w = t >> 6;
    __shared__ float lw[512];
    __shared__ float red[4][64];
    if (t < 128) ((f32x4*)lw)[t] = ((const f32x4*)(wq_w + (size_t)d*512))[t];
    __syncthreads();
    const float* col = actT + ROW_H*64 + b;
    float acc = 0.f;
    const int k0 = w*128;
    for (int kk=k0; kk<k0+128; kk+=8)
        DOT8(col, lw, kk, acc);
    red[w][b] = acc; __syncthreads();
    if (t < 64)
        Qs[(size_t)t*DD + d] = tanhf(wq_b[d] + red[0][t]+red[1][t]+red[2][t]+red[3][t]) * 0.0625f;
}

// ---------------- score: MFMA bf16, K-chunked reg pipeline, packed-B ----------------
#define SC_MFMA(KS, BF) \
  { const int cc_ = (KS)*4 + qw; \
    short8v a0_ = *(const short8v*)&As[lr*512 + ((cc_ ^ (lr&7))<<3)]; \
    short8v a1_ = *(const short8v*)&As[(16+lr)*512 + ((cc_ ^ (lr&7))<<3)]; \
    acc0 = __builtin_amdgcn_mfma_f32_16x16x32_bf16(a0_, BF, acc0, 0,0,0); \
    acc1 = __builtin_amdgcn_mfma_f32_16x16x32_bf16(a1_, BF, acc1, 0,0,0); }

#define SC_CHUNK(KC, B0,B1,B2,B3) \
    SC_MFMA((KC)*4+0, B0); SC_MFMA((KC)*4+1, B1); \
    SC_MFMA((KC)*4+2, B2); SC_MFMA((KC)*4+3, B3);

__global__ __launch_bounds__(1024, 4) void k_score_mfma(
    const float* __restrict__ enc, const short* __restrict__ Wb,
    const float* __restrict__ u, const float* __restrict__ v2,
    const float* __restrict__ Qs, const float* __restrict__ cov,
    const float* __restrict__ pmask, float* __restrict__ score)
{
    const int b  = blockIdx.y;
    const int l0 = blockIdx.x * 32;
    const int tid = threadIdx.x;
    const int wave = tid >> 6, lane = tid & 63;
    const int qw = lane >> 4, lr = lane & 15;
    const int col = wave*16 + lr;

    __shared__ __align__(16) short As[32*512];
    __shared__ float Red[16][32];

    const short* bp = Wb + (size_t)qw*2048 + col*8;
    short8v c0 = *(const short8v*)(bp +  0*8192);
    short8v c1 = *(const short8v*)(bp +  1*8192);
    short8v c2 = *(const short8v*)(bp +  2*8192);
    short8v c3 = *(const short8v*)(bp +  3*8192);

    const int arow = tid >> 5;
    const int af   = tid & 31;
    const bool aval = (l0 + arow) < LL;
    const float4* aptr = (const float4*)(enc + ((size_t)(b*LL + (aval ? l0+arow : 0)))*512);
    float4 areg[4];
    #pragma unroll
    for (int j=0; j<4; j++)
        areg[j] = aval ? aptr[af + j*32] : float4{0.f,0.f,0.f,0.f};

    #pragma unroll
    for (int j=0; j<4; j++){
        const int fi   = af + j*32;
        const int c    = fi >> 1;
        const int half = fi & 1;
        const int cs   = c ^ (arow & 7);
        short4v t4;
        t4[0]=f2bf(areg[j].x); t4[1]=f2bf(areg[j].y);
        t4[2]=f2bf(areg[j].z); t4[3]=f2bf(areg[j].w);
        *(short4v*)&As[arow*512 + cs*8 + half*4] = t4;
    }
    __syncthreads();

    f32x4 acc0 = f32x4{0.f,0.f,0.f,0.f};
    f32x4 acc1 = f32x4{0.f,0.f,0.f,0.f};

    short8v n0 = *(const short8v*)(bp +  4*8192);
    short8v n1 = *(const short8v*)(bp +  5*8192);
    short8v n2 = *(const short8v*)(bp +  6*8192);
    short8v n3 = *(const short8v*)(bp +  7*8192);
    SC_CHUNK(0, c0,c1,c2,c3);
    asm volatile("" : "+v"(n0),"+v"(n1),"+v"(n2),"+v"(n3));

    c0 = *(const short8v*)(bp +  8*8192);
    c1 = *(const short8v*)(bp +  9*8192);
    c2 = *(const short8v*)(bp + 10*8192);
    c3 = *(const short8v*)(bp + 11*8192);
    SC_CHUNK(1, n0,n1,n2,n3);
    asm volatile("" : "+v"(c0),"+v"(c1),"+v"(c2),"+v"(c3));

    n0 = *(const short8v*)(bp + 12*8192);
    n1 = *(const short8v*)(bp + 13*8192);
    n2 = *(const short8v*)(bp + 14*8192);
    n3 = *(const short8v*)(bp + 15*8192);
    SC_CHUNK(2, c0,c1,c2,c3);
    asm volatile("" : "+v"(n0),"+v"(n1),"+v"(n2),"+v"(n3));

    SC_CHUNK(3, n0,n1,n2,n3);

    const float qv = Qs[b*DD + col];
    const float uv = u[col];
    const float vv = v2[col];
    #pragma unroll
    for (int rf=0; rf<2; rf++){
        const f32x4 acc = rf ? acc1 : acc0;
        const int rbase = l0 + rf*16 + qw*4;
        float cv[4];
        if (rbase < LL){
            float4 c4v = *(const float4*)(cov + (size_t)b*LL + rbase);
            cv[0]=c4v.x; cv[1]=c4v.y; cv[2]=c4v.z; cv[3]=c4v.w;
        } else { cv[0]=cv[1]=cv[2]=cv[3]=0.f; }
        #pragma unroll
        for (int r=0; r<4; r++){
            float s = qv * tanhf(acc[r] + cv[r]*uv + vv);
            s += __shfl_xor(s,1); s += __shfl_xor(s,2);
            s += __shfl_xor(s,4); s += __shfl_xor(s,8);
            if (lr == 0) Red[wave][rf*16 + qw*4 + r] = s;
        }
    }
    __syncthreads();
    if (tid < 32){
        int l = l0 + tid;
        if (l < LL){
            float s = 0.f;
            #pragma unroll
            for (int w2=0; w2<16; w2++) s += Red[w2][tid];
            score[b*LL + l] = (pmask[b*LL+l] > 0.f) ? s : -1e18f;
        }
    }
}

// ---------------- fused softmax(L) + weighted context ------------------------------
__global__ __launch_bounds__(512) void k_wcsm(
    const float* __restrict__ score, const float* __restrict__ cov_in,
    const float* __restrict__ enc,
    float* __restrict__ attn_out, float* __restrict__ cov_out, float* __restrict__ wc)
{
    const int b = blockIdx.y, ch = blockIdx.x;
    const int t = threadIdx.x;
    __shared__ float sc[LL];
    __shared__ float red[512];

    float v = (t < LL) ? score[b*LL + t] : -INFINITY;
    red[t] = v; __syncthreads();
    for (int s=256;s>0;s>>=1){ if(t<s) red[t]=fmaxf(red[t],red[t+s]); __syncthreads(); }
    float m = red[0]; __syncthreads();
    float e = (t < LL) ? expf(v - m) : 0.f;
    if (t < LL) sc[t] = e;
    red[t] = e; __syncthreads();
    for (int s=256;s>0;s>>=1){ if(t<s) red[t]+=red[t+s]; __syncthreads(); }
    const float inv = 1.0f / red[0];

    const int l0 = ch * (LL/16);
    float s = 0.f;
    #pragma unroll 5
    for (int l=l0; l<l0+LL/16; ++l)
        s += sc[l] * enc[((size_t)(b*LL+l))*512 + t];
    atomicAdd(&wc[b*512 + t], s * inv);

    if (ch == 0 && t < LL){
        attn_out[b*LL + t] = sc[t] * inv;
        cov_out[b*LL + t]  = cov_in[b*LL + t];
    }
}

// ---------------- transpose wc -> actT rows 256..767 (LDS tile) --------------------
__global__ __launch_bounds__(256) void k_tr(const float* __restrict__ wc,
                                            float* __restrict__ actT)
{
    const int j0 = blockIdx.x * 64;
    __shared__ float tile[64][65];
    const int t = threadIdx.x;
    const int c = t & 63, r0 = t >> 6;
    #pragma unroll
    for (int bb = r0; bb < 64; bb += 4)
        tile[bb][c] = wc[(size_t)bb*512 + j0 + c];
    __syncthreads();
    #pragma unroll
    for (int jj = r0; jj < 64; jj += 4)
        actT[(ROW_WC + j0 + jj)*64 + c] = tile[c][jj];
}

// ============ pregen (+ p_gen in block 0), 8-deep load groups ======================
__global__ __launch_bounds__(256) void k_pregen(
    const float* __restrict__ actT,
    const float* __restrict__ pre_w, const float* __restrict__ pre_b,
    const float* __restrict__ pgen_w, const float* __restrict__ pgen_b,
    short* __restrict__ pregenb, float* __restrict__ pgen_out)
{
    const int d = blockIdx.x, t = threadIdx.x;
    const int b = t & 63, w = t >> 6;
    __shared__ float pw[768];
    __shared__ float red[4][64];
    if (t < 192) ((f32x4*)pw)[t] = ((const f32x4*)(pre_w + (size_t)d*768))[t];
    __syncthreads();
    const float* col = actT + ROW_WC*64 + b;
    float acc = 0.f;
    const int k0 = w*192;
    for (int kk=k0; kk<k0+192; kk+=8)
        DOT8(col, pw, kk, acc);
    red[w][b] = acc; __syncthreads();
    if (t < 64)
        pregenb[(size_t)t*DD + d] = f2bf(pre_b[d] + red[0][t]+red[1][t]+red[2][t]+red[3][t]);

    if (blockIdx.x == 0){
        __syncthreads();
        const float* colx = actT + b;
        float p = 0.f;
        const int j0 = w*320;
        for (int jj=j0; jj<j0+320; jj+=8)
            DOT8(colx, pgen_w, jj, p);
        red[w][b] = p; __syncthreads();
        if (t < 64)
            pgen_out[t] = sigmoidf_(red[0][t]+red[1][t]+red[2][t]+red[3][t] + pgen_b[0]);
    }
}

// ---------------- gen logits: K-chunked register pipeline, fused sm partials --------
#define GEN_SLICE(KS, RA, RB) \
  { short8v bb_; \
    bb_[0]=f2bf(RA[0]); bb_[1]=f2bf(RA[1]); bb_[2]=f2bf(RA[2]); bb_[3]=f2bf(RA[3]); \
    bb_[4]=f2bf(RB[0]); bb_[5]=f2bf(RB[1]); bb_[6]=f2bf(RB[2]); bb_[7]=f2bf(RB[3]); \
    const int cc_ = (KS)*4 + qw; \
    const int cs_ = (cc_ ^ (lr&7))<<3; \
    short8v aa0_ = *(const short8v*)&As[(lr     )*256 + cs_]; \
    short8v aa1_ = *(const short8v*)&As[(16+lr)*256 + cs_]; \
    short8v aa2_ = *(const short8v*)&As[(32+lr)*256 + cs_]; \
    short8v aa3_ = *(const short8v*)&As[(48+lr)*256 + cs_]; \
    acc0 = __builtin_amdgcn_mfma_f32_16x16x32_bf16(aa0_, bb_, acc0, 0,0,0); \
    acc1 = __builtin_amdgcn_mfma_f32_16x16x32_bf16(aa1_, bb_, acc1, 0,0,0); \
    acc2 = __builtin_amdgcn_mfma_f32_16x16x32_bf16(aa2_, bb_, acc2, 0,0,0); \
    acc3 = __builtin_amdgcn_mfma_f32_16x16x32_bf16(aa3_, bb_, acc3, 0,0,0); }

__global__ __launch_bounds__(256, 3) void k_gen_mfma(
    const short* __restrict__ pregenb, const float* __restrict__ gen_w,
    const float* __restrict__ gen_b, float* __restrict__ logits,
    float* __restrict__ blkM, float* __restrict__ blkS, int W)
{
    const int blk = blockIdx.x;
    const int v0 = blk * 64;
    const int tid = threadIdx.x;
    const int wave = tid>>6, lane = tid&63, qw = lane>>4, lr = lane&15;

    __shared__ __align__(16) short As[64*256];
    __shared__ float pm[4][64];
    __shared__ float ps[4][64];

    const int vrow = v0 + wave*16 + lr;
    const bool bval = (vrow < VV);
    const f32x4* bq = (const f32x4*)(gen_w + (size_t)(bval ? vrow : 0)*DD + qw*8);
    f32x4 a0 = bq[ 0], a1 = bq[ 1];
    f32x4 a2 = bq[ 8], a3 = bq[ 9];
    f32x4 a4 = bq[16], a5 = bq[17];
    f32x4 a6 = bq[24], a7 = bq[25];

    #pragma unroll
    for (int j=0; j<8; j++){
        int f = tid + j*256;
        int row = f >> 5, c = f & 31;
        short8v s = ((const short8v*)pregenb)[f];
        *(short8v*)&As[row*256 + ((c ^ (row&7))<<3)] = s;
    }
    __syncthreads();

    f32x4 acc0 = f32x4{0.f,0.f,0.f,0.f};
    f32x4 acc1 = f32x4{0.f,0.f,0.f,0.f};
    f32x4 acc2 = f32x4{0.f,0.f,0.f,0.f};
    f32x4 acc3 = f32x4{0.f,0.f,0.f,0.f};

    f32x4 b0 = bq[32], b1 = bq[33];
    f32x4 b2 = bq[40], b3 = bq[41];
    f32x4 b4 = bq[48], b5 = bq[49];
    f32x4 b6 = bq[56], b7 = bq[57];

    GEN_SLICE(0, a0, a1);
    GEN_SLICE(1, a2, a3);
    GEN_SLICE(2, a4, a5);
    GEN_SLICE(3, a6, a7);
    asm volatile("" : "+v"(b0),"+v"(b1),"+v"(b2),"+v"(b3),
                      "+v"(b4),"+v"(b5),"+v"(b6),"+v"(b7));
    GEN_SLICE(4, b0, b1);
    GEN_SLICE(5, b2, b3);
    GEN_SLICE(6, b4, b5);
    GEN_SLICE(7, b6, b7);

    f32x4 accs[4] = {acc0, acc1, acc2, acc3};
    const int v = v0 + wave*16 + lr;
    const bool vv = (v < VV);
    const float gb = vv ? gen_b[v] : 0.f;
    #pragma unroll
    for (int rf=0; rf<4; rf++){
        #pragma unroll
        for (int r=0; r<4; r++){
            float lg = accs[rf][r] + gb;
            int bt = rf*16 + qw*4 + r;
            if (vv) logits[(size_t)bt*W + v] = lg;
            float x = vv ? lg : -1e30f;
            float mx = x;
            mx = fmaxf(mx, __shfl_xor(mx,1));
            mx = fmaxf(mx, __shfl_xor(mx,2));
            mx = fmaxf(mx, __shfl_xor(mx,4));
            mx = fmaxf(mx, __shfl_xor(mx,8));
            float e = vv ? expf(x - mx) : 0.f;
            e += __shfl_xor(e,1); e += __shfl_xor(e,2);
            e += __shfl_xor(e,4); e += __shfl_xor(e,8);
            if (lr == 0){ pm[wave][bt] = mx; ps[wave][bt] = e; }
        }
    }
    __syncthreads();
    if (tid < 64){
        float M = fmaxf(fmaxf(pm[0][tid], pm[1][tid]), fmaxf(pm[2][tid], pm[3][tid]));
        float S = ps[0][tid]*expf(pm[0][tid]-M) + ps[1][tid]*expf(pm[1][tid]-M)
                + ps[2][tid]*expf(pm[2][tid]-M) + ps[3][tid]*expf(pm[3][tid]-M);
        blkM[(size_t)tid*NB + blk] = M;
        blkS[(size_t)tid*NB + blk] = S;
    }
}

// ---------------- reduce per-block partials -> M,S per batch -----------------------
__global__ __launch_bounds__(256) void k_vred(
    const float* __restrict__ blkM, const float* __restrict__ blkS,
    float* __restrict__ Ms, float* __restrict__ Ss)
{
    const int b = blockIdx.x, t = threadIdx.x;
    __shared__ float red[256];
    float m = -INFINITY;
    for (int i=t; i<NB; i+=256) m = fmaxf(m, blkM[(size_t)b*NB + i]);
    red[t]=m; __syncthreads();
    for (int s=128;s>0;s>>=1){ if(t<s) red[t]=fmaxf(red[t],red[t+s]); __syncthreads(); }
    const float M = red[0]; __syncthreads();
    float s = 0.f;
    for (int i=t; i<NB; i+=256) s += blkS[(size_t)b*NB + i] * expf(blkM[(size_t)b*NB + i] - M);
    red[t]=s; __syncthreads();
    for (int st=128;st>0;st>>=1){ if(t<st) red[t]+=red[t+st]; __syncthreads(); }
    if (t==0){ Ms[b]=M; Ss[b]=red[0]; }
}

// ---------------- normalize + zero ext ----------------------------------------------
__global__ void k_final(float* __restrict__ out, const float* __restrict__ Ms,
                        const float* __restrict__ Ss, const float* __restrict__ pgen, int W)
{
    size_t idx = (size_t)blockIdx.x*blockDim.x + threadIdx.x;
    if (idx >= (size_t)BB*W) return;
    int b = (int)(idx / W);
    int v = (int)(idx % W);
    float* row = out + (size_t)b*W;
    if (v < VV) row[v] = pgen[b] * expf(row[v]-Ms[b]) / Ss[b];
    else        row[v] = 0.f;
}

// ---------------- scatter-add copy dist ----------------------------------------------
__global__ void k_scatter(float* __restrict__ out, const int* __restrict__ ext,
                          const float* __restrict__ attn, const float* __restrict__ pgen, int W)
{
    int idx = blockIdx.x*blockDim.x + threadIdx.x;
    if (idx >= BB*LL) return;
    int b = idx / LL;
    atomicAdd(out + (size_t)b*W + ext[idx], (1.0f - pgen[b]) * attn[idx]);
}

extern "C" void kernel_launch(void* const* d_in, const int* in_sizes, int n_in,
                              void* d_out, int out_size, void* d_ws, size_t ws_size,
                              hipStream_t stream)
{
    const int*   inp     = (const int*)  d_in[0];
    const float* hh      = (const float*)d_in[1];
    const float* hc      = (const float*)d_in[2];
    const float* enc     = (const float*)d_in[3];
    const float* prev    = (const float*)d_in[4];
    const int*   ext     = (const int*)  d_in[5];
    const float* cov     = (const float*)d_in[6];
    const float* pmask   = (const float*)d_in[7];
    const int*   step_p  = (const int*)  d_in[9];
    const float* emb_w   = (const float*)d_in[10];
    const float* lin_w   = (const float*)d_in[11];
    const float* lin_b   = (const float*)d_in[12];
    const float* w_ih    = (const float*)d_in[13];
    const float* w_hh    = (const float*)d_in[14];
    const float* b_ih    = (const float*)d_in[15];
    const float* b_hh    = (const float*)d_in[16];
    const float* rhw     = (const float*)d_in[17];
    const float* rhb     = (const float*)d_in[18];
    const float* rcw     = (const float*)d_in[19];
    const float* rcb     = (const float*)d_in[20];
    const float* wq_w    = (const float*)d_in[21];
    const float* wq_b    = (const float*)d_in[22];
    const float* cov_w   = (const float*)d_in[23];
    const float* cov_b   = (const float*)d_in[24];
    const float* wk_w    = (const float*)d_in[25];
    const float* wk_b    = (const float*)d_in[26];
    const float* pre_w   = (const float*)d_in[27];
    const float* pre_b   = (const float*)d_in[28];
    const float* gen_w   = (const float*)d_in[29];
    const float* gen_b   = (const float*)d_in[30];
    const float* pgen_w  = (const float*)d_in[31];
    const float* pgen_b  = (const float*)d_in[32];

    const int W = out_size / BB - 4*DD - 2*LL - 1;  // V + ex_size = 50200
    float* out     = (float*)d_out;
    float* o_final = out;
    float* o_h     = out + (size_t)BB*W;
    float* o_c     = o_h + BB*DD;
    float* o_wc    = o_c + BB*DD;
    float* o_attn  = o_wc + BB*2*DD;
    float* o_cov   = o_attn + BB*LL;
    float* o_pgen  = o_cov + BB*LL;

    // workspace
    float* W_actT   = (float*)d_ws;                  // 1280*64 floats
    float* W_whT    = W_actT + 1280*64;              // B*D
    float* W_wcT0   = W_whT + BB*DD;                 // B*D
    float* W_q      = W_wcT0 + BB*DD;                // B*D
    float* W_score  = W_q + BB*DD;                   // B*L
    float* W_m      = W_score + BB*LL;               // B
    float* W_s      = W_m + BB;                      // B
    float* W_u      = W_s + BB;                      // D
    float* W_v2     = W_u + DD;                      // D
    float* W_blkM   = W_v2 + DD;                     // B*NB
    float* W_blkS   = W_blkM + (size_t)BB*NB;        // B*NB
    short* W_wb     = (short*)(W_blkS + (size_t)BB*NB);  // 64*2048 shorts
    short* W_pgb    = (short*)(W_wb + 64*2048);          // B*D bf16

    k_front1<<<dim3(DD,4), 256, 0, stream>>>(inp, hh, hc, prev, emb_w, lin_w, lin_b,
                                             rhw, rhb, rcw, rcb, step_p,
                                             wk_w, wk_b, cov_w, cov_b,
                                             W_actT, W_whT, W_wcT0, W_wb, W_u, W_v2, o_wc);
    k_gl<<<DD, 256, 0, stream>>>(W_actT, W_whT, W_wcT0, w_ih, w_hh, b_ih, b_hh,
                                 o_h, o_c, W_actT);
    k_q2<<<DD, 256, 0, stream>>>(W_actT, wq_w, wq_b, W_q);
    k_score_mfma<<<dim3(13, BB), 1024, 0, stream>>>(enc, W_wb, W_u, W_v2, W_q, cov, pmask, W_score);
    k_wcsm<<<dim3(16, BB), 512, 0, stream>>>(W_score, cov, enc, o_attn, o_cov, o_wc);
    k_tr<<<8, 256, 0, stream>>>(o_wc, W_actT);
    k_pregen<<<DD, 256, 0, stream>>>(W_actT, pre_w, pre_b, pgen_w, pgen_b, W_pgb, o_pgen);
    k_gen_mfma<<<NB, 256, 0, stream>>>(W_pgb, gen_w, gen_b, o_final, W_blkM, W_blkS, W);
    k_vred<<<BB, 256, 0, stream>>>(W_blkM, W_blkS, W_m, W_s);
    k_final<<<(int)(((size_t)BB*W+255)/256), 256, 0, stream>>>(o_final, W_m, W_s, o_pgen, W);
    k_scatter<<<(BB*LL+255)/256, 256, 0, stream>>>(o_final, ext, o_attn, o_pgen, W);
}

// Round 16
// 132.360 us; speedup vs baseline: 1.0774x; 1.0449x over previous
//
#include <hip/hip_runtime.h>
#include <math.h>

// V=50000, E=128, D=256, L=400, B=64
#define BB 64
#define DD 256
#define LL 400
#define VV 50000
#define EE 128
#define NB 782   // ceil(VV/64)

typedef __attribute__((ext_vector_type(8))) short short8v;
typedef __attribute__((ext_vector_type(4))) short short4v;
typedef __attribute__((ext_vector_type(4))) float f32x4;

__device__ __forceinline__ float sigmoidf_(float x){ return 1.0f/(1.0f+expf(-x)); }

__device__ __forceinline__ short f2bf(float f){
    unsigned u = __builtin_bit_cast(unsigned, f);
    u += 0x7fffu + ((u>>16)&1u);
    return (short)(u>>16);
}
__device__ __forceinline__ float bf2f(unsigned short b){
    unsigned u = ((unsigned)b) << 16;
    return __builtin_bit_cast(float, u);
}

// actT layout: rows 0..255 x | 256..767 wc | 768..1023 h | 1024..1279 c
#define ROW_X   0
#define ROW_WC  256
#define ROW_H   768
#define ROW_C   1024

#define DOT8(col, wptr, kk, acc) { \
    float a0_=(col)[((kk)+0)*64], a1_=(col)[((kk)+1)*64], a2_=(col)[((kk)+2)*64], a3_=(col)[((kk)+3)*64], \
          a4_=(col)[((kk)+4)*64], a5_=(col)[((kk)+5)*64], a6_=(col)[((kk)+6)*64], a7_=(col)[((kk)+7)*64]; \
    asm volatile("" : "+v"(a0_),"+v"(a1_),"+v"(a2_),"+v"(a3_),"+v"(a4_),"+v"(a5_),"+v"(a6_),"+v"(a7_)); \
    acc += a0_*(wptr)[(kk)+0] + a1_*(wptr)[(kk)+1] + a2_*(wptr)[(kk)+2] + a3_*(wptr)[(kk)+3] \
         + a4_*(wptr)[(kk)+4] + a5_*(wptr)[(kk)+5] + a6_*(wptr)[(kk)+6] + a7_*(wptr)[(kk)+7]; }

__device__ __forceinline__ float dot4v(f32x4 a, f32x4 b){
    return a[0]*b[0] + a[1]*b[1] + a[2]*b[2] + a[3]*b[3];
}

// ============ FRONT STAGE 1: x, h, c (+ score prep, + wcpart/S zeroing) ============
__global__ __launch_bounds__(256) void k_front1(
    const int* __restrict__ inp, const float* __restrict__ hh, const float* __restrict__ hc,
    const float* __restrict__ prev, const float* __restrict__ emb_w,
    const float* __restrict__ lin_w, const float* __restrict__ lin_b,
    const float* __restrict__ rhw, const float* __restrict__ rhb,
    const float* __restrict__ rcw, const float* __restrict__ rcb,
    const int* __restrict__ step_p,
    const float* __restrict__ wk_w, const float* __restrict__ wk_b,
    const float* __restrict__ cov_w, const float* __restrict__ cov_b,
    float* __restrict__ actT, float* __restrict__ WhT, float* __restrict__ WcT0,
    short* __restrict__ Wb, float* __restrict__ u, float* __restrict__ v2,
    float* __restrict__ wcpart, float* __restrict__ Ssum)
{
    const int d = blockIdx.x, y = blockIdx.y, t = threadIdx.x;
    const int b = t >> 2, kq = t & 3;
    __shared__ float lw[640];
    __shared__ float red[256];

    if (y == 3){
        // zero wc partial accumulator + per-batch exp-sum
        if (t < 128) wcpart[d*128 + t] = 0.f;
        if (d == 0 && t >= 128 && t < 192) Ssum[t-128] = 0.f;
        const float* row = wk_w + (size_t)d*512;
        float su=0.f, sv=0.f;
        for (int j=t; j<512; j+=256){
            float wv = row[j];
            Wb[(size_t)(j>>3)*2048 + d*8 + (j&7)] = f2bf(wv);
            su += wv*cov_w[j];
            sv += wv*cov_b[j];
        }
        float* rs = lw;
        float* rv = red;
        rs[t]=su; rv[t]=sv; __syncthreads();
        for (int s=128;s>0;s>>=1){ if(t<s){rs[t]+=rs[t+s]; rv[t]+=rv[t+s];} __syncthreads(); }
        if (t==0){ u[d]=rs[0]; v2[d]=rv[0] + wk_b[d]; }
        return;
    }

    if (y == 0){
        if (t < 160) ((f32x4*)lw)[t] = ((const f32x4*)(lin_w + (size_t)d*640))[t];
        __syncthreads();
        const f32x4* lw4 = (const f32x4*)lw;
        const f32x4* er4 = (const f32x4*)(emb_w + (size_t)inp[b]*EE);
        const f32x4* pv4 = (const f32x4*)(prev + (size_t)b*512);
        float acc = 0.f;
        for (int i=kq; i<160; i+=16){
            f32x4 v0 = (i    < 32) ? er4[i]    : pv4[i-32];
            f32x4 v1 = (i+4  < 32) ? er4[i+4]  : pv4[i-28];
            f32x4 v2_ = pv4[i-24];
            f32x4 v3 = pv4[i-20];
            if (i+8  < 32) v2_ = er4[i+8];
            if (i+12 < 32) v3 = er4[i+12];
            asm volatile("" : "+v"(v0),"+v"(v1),"+v"(v2_),"+v"(v3));
            acc += dot4v(v0, lw4[i]) + dot4v(v1, lw4[i+4])
                 + dot4v(v2_, lw4[i+8]) + dot4v(v3, lw4[i+12]);
        }
        acc += __shfl_xor(acc,1); acc += __shfl_xor(acc,2);
        if (kq == 0) actT[(ROW_X + d)*64 + b] = lin_b[d] + acc;
        return;
    }

    const float* src  = (y==1) ? hh  : hc;
    float*       dstT = (y==1) ? WhT : WcT0;
    if (*step_p == 0){
        const float* wrow = ((y==1) ? rhw : rcw) + (size_t)d*512;
        const float  bias = ((y==1) ? rhb : rcb)[d];
        if (t < 128) ((f32x4*)lw)[t] = ((const f32x4*)wrow)[t];
        __syncthreads();
        const f32x4* lw4 = (const f32x4*)lw;
        const f32x4* s0 = (const f32x4*)(src + (size_t)b*DD);
        const f32x4* s1 = (const f32x4*)(src + (size_t)BB*DD + (size_t)b*DD);
        float acc = 0.f;
        for (int i=kq; i<128; i+=16){
            f32x4 v0 = (i    < 64) ? s0[i]    : s1[i-64];
            f32x4 v1 = (i+4  < 64) ? s0[i+4]  : s1[i-60];
            f32x4 v2_ = (i+8 < 64) ? s0[i+8]  : s1[i-56];
            f32x4 v3 = (i+12 < 64) ? s0[i+12] : s1[i-52];
            asm volatile("" : "+v"(v0),"+v"(v1),"+v"(v2_),"+v"(v3));
            acc += dot4v(v0, lw4[i]) + dot4v(v1, lw4[i+4])
                 + dot4v(v2_, lw4[i+8]) + dot4v(v3, lw4[i+12]);
        }
        acc += __shfl_xor(acc,1); acc += __shfl_xor(acc,2);
        if (kq == 0){
            float a = bias + acc;
            dstT[d*64 + b] = a>0.f ? a : 0.f;
        }
    } else {
        if (t < 64) dstT[d*64 + t] = src[(size_t)t*DD + d];
    }
}

// ============ FRONT STAGE 2: gates + LSTM ==========================================
__global__ __launch_bounds__(256) void k_gl(
    const float* __restrict__ actT, const float* __restrict__ WhT, const float* __restrict__ WcT0,
    const float* __restrict__ w_ih, const float* __restrict__ w_hh,
    const float* __restrict__ b_ih, const float* __restrict__ b_hh,
    float* __restrict__ o_h, float* __restrict__ o_c, float* __restrict__ actT_out)
{
    const int d = blockIdx.x, t = threadIdx.x;
    const int b = t & 63, gi = t >> 6;
    __shared__ float wih[4][256];
    __shared__ float whh[4][256];
    __shared__ float gl[4][64];

    const int gr = gi*DD + d;
    ((f32x4*)&wih[gi][0])[b] = ((const f32x4*)(w_ih + (size_t)gr*DD))[b];
    ((f32x4*)&whh[gi][0])[b] = ((const f32x4*)(w_hh + (size_t)gr*DD))[b];
    __syncthreads();

    const float* xcol = actT + ROW_X*64 + b;
    const float* hcol = WhT + b;
    float a0=0.f, a1=0.f;
    for (int kk=0; kk<256; kk+=8){
        DOT8(xcol, &wih[gi][0], kk, a0);
        DOT8(hcol, &whh[gi][0], kk, a1);
    }
    gl[gi][b] = a0 + a1 + b_ih[gr] + b_hh[gr];
    __syncthreads();

    if (t < 64){
        float iv = sigmoidf_(gl[0][t]);
        float fv = sigmoidf_(gl[1][t]);
        float gv = tanhf(gl[2][t]);
        float ov = sigmoidf_(gl[3][t]);
        float cn = fv*WcT0[d*64 + t] + iv*gv;
        float hn = ov*tanhf(cn);
        o_c[(size_t)t*DD + d] = cn;
        o_h[(size_t)t*DD + d] = hn;
        actT_out[(ROW_C + d)*64 + t] = cn;
        actT_out[(ROW_H + d)*64 + t] = hn;
    }
}

// ============ FRONT STAGE 3: Q =====================================================
__global__ __launch_bounds__(256) void k_q2(
    const float* __restrict__ actT,
    const float* __restrict__ wq_w, const float* __restrict__ wq_b,
    float* __restrict__ Qs)
{
    const int d = blockIdx.x, t = threadIdx.x;
    const int b = t & 63, w = t >> 6;
    __shared__ float lw[512];
    __shared__ float red[4][64];
    if (t < 128) ((f32x4*)lw)[t] = ((const f32x4*)(wq_w + (size_t)d*512))[t];
    __syncthreads();
    const float* col = actT + ROW_H*64 + b;
    float acc = 0.f;
    const int k0 = w*128;
    for (int kk=k0; kk<k0+128; kk+=8)
        DOT8(col, lw, kk, acc);
    red[w][b] = acc; __syncthreads();
    if (t < 64)
        Qs[(size_t)t*DD + d] = tanhf(wq_b[d] + red[0][t]+red[1][t]+red[2][t]+red[3][t]) * 0.0625f;
}

// ---------------- score: MFMA + fused exp + Σe + unnormalized wc partials -----------
// |score| <= 256 * (1/16) = 16  =>  exp(score) safe without max subtraction.
#define SC_MFMA(KS, BF) \
  { const int cc_ = (KS)*4 + qw; \
    short8v a0_ = *(const short8v*)&As[lr*512 + ((cc_ ^ (lr&7))<<3)]; \
    short8v a1_ = *(const short8v*)&As[(16+lr)*512 + ((cc_ ^ (lr&7))<<3)]; \
    acc0 = __builtin_amdgcn_mfma_f32_16x16x32_bf16(a0_, BF, acc0, 0,0,0); \
    acc1 = __builtin_amdgcn_mfma_f32_16x16x32_bf16(a1_, BF, acc1, 0,0,0); }

#define SC_CHUNK(KC, B0,B1,B2,B3) \
    SC_MFMA((KC)*4+0, B0); SC_MFMA((KC)*4+1, B1); \
    SC_MFMA((KC)*4+2, B2); SC_MFMA((KC)*4+3, B3);

__global__ __launch_bounds__(1024, 4) void k_score_mfma(
    const float* __restrict__ enc, const short* __restrict__ Wb,
    const float* __restrict__ u, const float* __restrict__ v2,
    const float* __restrict__ Qs, const float* __restrict__ cov,
    const float* __restrict__ pmask,
    float* __restrict__ Ev, float* __restrict__ Ssum, float* __restrict__ wcpart)
{
    const int b  = blockIdx.y;
    const int l0 = blockIdx.x * 32;
    const int tid = threadIdx.x;
    const int wave = tid >> 6, lane = tid & 63;
    const int qw = lane >> 4, lr = lane & 15;
    const int col = wave*16 + lr;

    __shared__ __align__(16) short As[32*512];
    __shared__ float Red[16][32];
    __shared__ float esh[32];

    const short* bp = Wb + (size_t)qw*2048 + col*8;
    short8v c0 = *(const short8v*)(bp +  0*8192);
    short8v c1 = *(const short8v*)(bp +  1*8192);
    short8v c2 = *(const short8v*)(bp +  2*8192);
    short8v c3 = *(const short8v*)(bp +  3*8192);

    const int arow = tid >> 5;
    const int af   = tid & 31;
    const bool aval = (l0 + arow) < LL;
    const float4* aptr = (const float4*)(enc + ((size_t)(b*LL + (aval ? l0+arow : 0)))*512);
    float4 areg[4];
    #pragma unroll
    for (int j=0; j<4; j++)
        areg[j] = aval ? aptr[af + j*32] : float4{0.f,0.f,0.f,0.f};

    #pragma unroll
    for (int j=0; j<4; j++){
        const int fi   = af + j*32;
        const int c    = fi >> 1;
        const int half = fi & 1;
        const int cs   = c ^ (arow & 7);
        short4v t4;
        t4[0]=f2bf(areg[j].x); t4[1]=f2bf(areg[j].y);
        t4[2]=f2bf(areg[j].z); t4[3]=f2bf(areg[j].w);
        *(short4v*)&As[arow*512 + cs*8 + half*4] = t4;
    }
    __syncthreads();

    f32x4 acc0 = f32x4{0.f,0.f,0.f,0.f};
    f32x4 acc1 = f32x4{0.f,0.f,0.f,0.f};

    short8v n0 = *(const short8v*)(bp +  4*8192);
    short8v n1 = *(const short8v*)(bp +  5*8192);
    short8v n2 = *(const short8v*)(bp +  6*8192);
    short8v n3 = *(const short8v*)(bp +  7*8192);
    SC_CHUNK(0, c0,c1,c2,c3);
    asm volatile("" : "+v"(n0),"+v"(n1),"+v"(n2),"+v"(n3));

    c0 = *(const short8v*)(bp +  8*8192);
    c1 = *(const short8v*)(bp +  9*8192);
    c2 = *(const short8v*)(bp + 10*8192);
    c3 = *(const short8v*)(bp + 11*8192);
    SC_CHUNK(1, n0,n1,n2,n3);
    asm volatile("" : "+v"(c0),"+v"(c1),"+v"(c2),"+v"(c3));

    n0 = *(const short8v*)(bp + 12*8192);
    n1 = *(const short8v*)(bp + 13*8192);
    n2 = *(const short8v*)(bp + 14*8192);
    n3 = *(const short8v*)(bp + 15*8192);
    SC_CHUNK(2, c0,c1,c2,c3);
    asm volatile("" : "+v"(n0),"+v"(n1),"+v"(n2),"+v"(n3));

    SC_CHUNK(3, n0,n1,n2,n3);

    const float qv = Qs[b*DD + col];
    const float uv = u[col];
    const float vv = v2[col];
    #pragma unroll
    for (int rf=0; rf<2; rf++){
        const f32x4 acc = rf ? acc1 : acc0;
        const int rbase = l0 + rf*16 + qw*4;
        float cv[4];
        if (rbase < LL){
            float4 c4v = *(const float4*)(cov + (size_t)b*LL + rbase);
            cv[0]=c4v.x; cv[1]=c4v.y; cv[2]=c4v.z; cv[3]=c4v.w;
        } else { cv[0]=cv[1]=cv[2]=cv[3]=0.f; }
        #pragma unroll
        for (int r=0; r<4; r++){
            float s = qv * tanhf(acc[r] + cv[r]*uv + vv);
            s += __shfl_xor(s,1); s += __shfl_xor(s,2);
            s += __shfl_xor(s,4); s += __shfl_xor(s,8);
            if (lr == 0) Red[wave][rf*16 + qw*4 + r] = s;
        }
    }
    __syncthreads();
    // exp (no max needed) + Σe
    if (tid < 32){
        int l = l0 + tid;
        float e = 0.f;
        if (l < LL){
            float s = 0.f;
            #pragma unroll
            for (int w2=0; w2<16; w2++) s += Red[w2][tid];
            e = (pmask[b*LL+l] > 0.f) ? expf(s) : 0.f;
            Ev[b*LL + l] = e;
        }
        esh[tid] = e;
        float se = e;
        se += __shfl_xor(se,1); se += __shfl_xor(se,2);
        se += __shfl_xor(se,4); se += __shfl_xor(se,8);
        se += __shfl_xor(se,16);
        if (tid == 0) atomicAdd(&Ssum[b], se);
    }
    __syncthreads();
    // unnormalized wc partial from the LDS bf16 A-tile: wc_j += Σ_l e_l * enc[l][j]
    if (tid < 512){
        const int c  = tid >> 3;    // 16B chunk of the row
        const int p  = tid & 7;     // position within chunk
        float acc = 0.f;
        #pragma unroll
        for (int l=0; l<32; l++){
            unsigned short bits = (unsigned short)As[l*512 + ((c ^ (l&7))<<3) + p];
            acc += esh[l] * bf2f(bits);
        }
        atomicAdd(&wcpart[b*512 + tid], acc);
    }
}

// ---------------- attn + coverage outputs ------------------------------------------
__global__ __launch_bounds__(512) void k_attn(
    const float* __restrict__ Ev, const float* __restrict__ Ssum,
    const float* __restrict__ cov_in,
    float* __restrict__ attn_out, float* __restrict__ cov_out)
{
    const int b = blockIdx.x, t = threadIdx.x;
    if (t < LL){
        const float inv = 1.0f / Ssum[b];
        attn_out[b*LL + t] = Ev[b*LL + t] * inv;
        cov_out[b*LL + t]  = cov_in[b*LL + t];
    }
}

// ---------------- transpose + normalize wc -> o_wc and actT rows 256..767 ----------
__global__ __launch_bounds__(256) void k_tr(const float* __restrict__ wcpart,
                                            const float* __restrict__ Ssum,
                                            float* __restrict__ o_wc,
                                            float* __restrict__ actT)
{
    const int j0 = blockIdx.x * 64;
    __shared__ float tile[64][65];
    __shared__ float invs[64];
    const int t = threadIdx.x;
    const int c = t & 63, r0 = t >> 6;
    if (t < 64) invs[t] = 1.0f / Ssum[t];
    __syncthreads();
    #pragma unroll
    for (int bb = r0; bb < 64; bb += 4){
        float v = wcpart[(size_t)bb*512 + j0 + c] * invs[bb];
        tile[bb][c] = v;
        o_wc[(size_t)bb*512 + j0 + c] = v;
    }
    __syncthreads();
    #pragma unroll
    for (int jj = r0; jj < 64; jj += 4)
        actT[(ROW_WC + j0 + jj)*64 + c] = tile[c][jj];
}

// ============ pregen (+ p_gen in block 0) ==========================================
__global__ __launch_bounds__(256) void k_pregen(
    const float* __restrict__ actT,
    const float* __restrict__ pre_w, const float* __restrict__ pre_b,
    const float* __restrict__ pgen_w, const float* __restrict__ pgen_b,
    short* __restrict__ pregenb, float* __restrict__ pgen_out)
{
    const int d = blockIdx.x, t = threadIdx.x;
    const int b = t & 63, w = t >> 6;
    __shared__ float pw[768];
    __shared__ float red[4][64];
    if (t < 192) ((f32x4*)pw)[t] = ((const f32x4*)(pre_w + (size_t)d*768))[t];
    __syncthreads();
    const float* col = actT + ROW_WC*64 + b;
    float acc = 0.f;
    const int k0 = w*192;
    for (int kk=k0; kk<k0+192; kk+=8)
        DOT8(col, pw, kk, acc);
    red[w][b] = acc; __syncthreads();
    if (t < 64)
        pregenb[(size_t)t*DD + d] = f2bf(pre_b[d] + red[0][t]+red[1][t]+red[2][t]+red[3][t]);

    if (blockIdx.x == 0){
        __syncthreads();
        const float* colx = actT + b;
        float p = 0.f;
        const int j0 = w*320;
        for (int jj=j0; jj<j0+320; jj+=8)
            DOT8(colx, pgen_w, jj, p);
        red[w][b] = p; __syncthreads();
        if (t < 64)
            pgen_out[t] = sigmoidf_(red[0][t]+red[1][t]+red[2][t]+red[3][t] + pgen_b[0]);
    }
}

// ---------------- gen logits: MFMA, bf16 logits to workspace, fused sm partials -----
#define GEN_SLICE(KS, RA, RB) \
  { short8v bb_; \
    bb_[0]=f2bf(RA[0]); bb_[1]=f2bf(RA[1]); bb_[2]=f2bf(RA[2]); bb_[3]=f2bf(RA[3]); \
    bb_[4]=f2bf(RB[0]); bb_[5]=f2bf(RB[1]); bb_[6]=f2bf(RB[2]); bb_[7]=f2bf(RB[3]); \
    const int cc_ = (KS)*4 + qw; \
    const int cs_ = (cc_ ^ (lr&7))<<3; \
    short8v aa0_ = *(const short8v*)&As[(lr     )*256 + cs_]; \
    short8v aa1_ = *(const short8v*)&As[(16+lr)*256 + cs_]; \
    short8v aa2_ = *(const short8v*)&As[(32+lr)*256 + cs_]; \
    short8v aa3_ = *(const short8v*)&As[(48+lr)*256 + cs_]; \
    acc0 = __builtin_amdgcn_mfma_f32_16x16x32_bf16(aa0_, bb_, acc0, 0,0,0); \
    acc1 = __builtin_amdgcn_mfma_f32_16x16x32_bf16(aa1_, bb_, acc1, 0,0,0); \
    acc2 = __builtin_amdgcn_mfma_f32_16x16x32_bf16(aa2_, bb_, acc2, 0,0,0); \
    acc3 = __builtin_amdgcn_mfma_f32_16x16x32_bf16(aa3_, bb_, acc3, 0,0,0); }

__global__ __launch_bounds__(256, 3) void k_gen_mfma(
    const short* __restrict__ pregenb, const float* __restrict__ gen_w,
    const float* __restrict__ gen_b, short* __restrict__ lgb,
    float* __restrict__ blkM, float* __restrict__ blkS)
{
    const int blk = blockIdx.x;
    const int v0 = blk * 64;
    const int tid = threadIdx.x;
    const int wave = tid>>6, lane = tid&63, qw = lane>>4, lr = lane&15;

    __shared__ __align__(16) short As[64*256];
    __shared__ float pm[4][64];
    __shared__ float ps[4][64];

    const int vrow = v0 + wave*16 + lr;
    const bool bval = (vrow < VV);
    const f32x4* bq = (const f32x4*)(gen_w + (size_t)(bval ? vrow : 0)*DD + qw*8);
    f32x4 a0 = bq[ 0], a1 = bq[ 1];
    f32x4 a2 = bq[ 8], a3 = bq[ 9];
    f32x4 a4 = bq[16], a5 = bq[17];
    f32x4 a6 = bq[24], a7 = bq[25];

    #pragma unroll
    for (int j=0; j<8; j++){
        int f = tid + j*256;
        int row = f >> 5, c = f & 31;
        short8v s = ((const short8v*)pregenb)[f];
        *(short8v*)&As[row*256 + ((c ^ (row&7))<<3)] = s;
    }
    __syncthreads();

    f32x4 acc0 = f32x4{0.f,0.f,0.f,0.f};
    f32x4 acc1 = f32x4{0.f,0.f,0.f,0.f};
    f32x4 acc2 = f32x4{0.f,0.f,0.f,0.f};
    f32x4 acc3 = f32x4{0.f,0.f,0.f,0.f};

    f32x4 b0 = bq[32], b1 = bq[33];
    f32x4 b2 = bq[40], b3 = bq[41];
    f32x4 b4 = bq[48], b5 = bq[49];
    f32x4 b6 = bq[56], b7 = bq[57];

    GEN_SLICE(0, a0, a1);
    GEN_SLICE(1, a2, a3);
    GEN_SLICE(2, a4, a5);
    GEN_SLICE(3, a6, a7);
    asm volatile("" : "+v"(b0),"+v"(b1),"+v"(b2),"+v"(b3),
                      "+v"(b4),"+v"(b5),"+v"(b6),"+v"(b7));
    GEN_SLICE(4, b0, b1);
    GEN_SLICE(5, b2, b3);
    GEN_SLICE(6, b4, b5);
    GEN_SLICE(7, b6, b7);

    f32x4 accs[4] = {acc0, acc1, acc2, acc3};
    const int v = v0 + wave*16 + lr;
    const bool vv = (v < VV);
    const float gb = vv ? gen_b[v] : 0.f;
    #pragma unroll
    for (int rf=0; rf<4; rf++){
        #pragma unroll
        for (int r=0; r<4; r++){
            float lg = accs[rf][r] + gb;
            int bt = rf*16 + qw*4 + r;
            if (vv) lgb[(size_t)bt*VV + v] = f2bf(lg);
            float x = vv ? lg : -1e30f;
            float mx = x;
            mx = fmaxf(mx, __shfl_xor(mx,1));
            mx = fmaxf(mx, __shfl_xor(mx,2));
            mx = fmaxf(mx, __shfl_xor(mx,4));
            mx = fmaxf(mx, __shfl_xor(mx,8));
            float e = vv ? expf(x - mx) : 0.f;
            e += __shfl_xor(e,1); e += __shfl_xor(e,2);
            e += __shfl_xor(e,4); e += __shfl_xor(e,8);
            if (lr == 0){ pm[wave][bt] = mx; ps[wave][bt] = e; }
        }
    }
    __syncthreads();
    if (tid < 64){
        float M = fmaxf(fmaxf(pm[0][tid], pm[1][tid]), fmaxf(pm[2][tid], pm[3][tid]));
        float S = ps[0][tid]*expf(pm[0][tid]-M) + ps[1][tid]*expf(pm[1][tid]-M)
                + ps[2][tid]*expf(pm[2][tid]-M) + ps[3][tid]*expf(pm[3][tid]-M);
        blkM[(size_t)tid*NB + blk] = M;
        blkS[(size_t)tid*NB + blk] = S;
    }
}

// ---------------- reduce per-block partials -> M,S per batch -----------------------
__global__ __launch_bounds__(256) void k_vred(
    const float* __restrict__ blkM, const float* __restrict__ blkS,
    float* __restrict__ Ms, float* __restrict__ Ss)
{
    const int b = blockIdx.x, t = threadIdx.x;
    __shared__ float red[256];
    float m = -INFINITY;
    for (int i=t; i<NB; i+=256) m = fmaxf(m, blkM[(size_t)b*NB + i]);
    red[t]=m; __syncthreads();
    for (int s=128;s>0;s>>=1){ if(t<s) red[t]=fmaxf(red[t],red[t+s]); __syncthreads(); }
    const float M = red[0]; __syncthreads();
    float s = 0.f;
    for (int i=t; i<NB; i+=256) s += blkS[(size_t)b*NB + i] * expf(blkM[(size_t)b*NB + i] - M);
    red[t]=s; __syncthreads();
    for (int st=128;st>0;st>>=1){ if(t<st) red[t]+=red[t+st]; __syncthreads(); }
    if (t==0){ Ms[b]=M; Ss[b]=red[0]; }
}

// ---------------- normalize (bf16 logits in) + zero ext ----------------------------
__global__ void k_final(const short* __restrict__ lgb, float* __restrict__ out,
                        const float* __restrict__ Ms, const float* __restrict__ Ss,
                        const float* __restrict__ pgen, int W)
{
    size_t idx = (size_t)blockIdx.x*blockDim.x + threadIdx.x;
    if (idx >= (size_t)BB*W) return;
    int b = (int)(idx / W);
    int v = (int)(idx % W);
    float* row = out + (size_t)b*W;
    if (v < VV){
        float lg = bf2f((unsigned short)lgb[(size_t)b*VV + v]);
        row[v] = pgen[b] * expf(lg - Ms[b]) / Ss[b];
    } else row[v] = 0.f;
}

// ---------------- scatter-add copy dist ----------------------------------------------
__global__ void k_scatter(float* __restrict__ out, const int* __restrict__ ext,
                          const float* __restrict__ attn, const float* __restrict__ pgen, int W)
{
    int idx = blockIdx.x*blockDim.x + threadIdx.x;
    if (idx >= BB*LL) return;
    int b = idx / LL;
    atomicAdd(out + (size_t)b*W + ext[idx], (1.0f - pgen[b]) * attn[idx]);
}

extern "C" void kernel_launch(void* const* d_in, const int* in_sizes, int n_in,
                              void* d_out, int out_size, void* d_ws, size_t ws_size,
                              hipStream_t stream)
{
    const int*   inp     = (const int*)  d_in[0];
    const float* hh      = (const float*)d_in[1];
    const float* hc      = (const float*)d_in[2];
    const float* enc     = (const float*)d_in[3];
    const float* prev    = (const float*)d_in[4];
    const int*   ext     = (const int*)  d_in[5];
    const float* cov     = (const float*)d_in[6];
    const float* pmask   = (const float*)d_in[7];
    const int*   step_p  = (const int*)  d_in[9];
    const float* emb_w   = (const float*)d_in[10];
    const float* lin_w   = (const float*)d_in[11];
    const float* lin_b   = (const float*)d_in[12];
    const float* w_ih    = (const float*)d_in[13];
    const float* w_hh    = (const float*)d_in[14];
    const float* b_ih    = (const float*)d_in[15];
    const float* b_hh    = (const float*)d_in[16];
    const float* rhw     = (const float*)d_in[17];
    const float* rhb     = (const float*)d_in[18];
    const float* rcw     = (const float*)d_in[19];
    const float* rcb     = (const float*)d_in[20];
    const float* wq_w    = (const float*)d_in[21];
    const float* wq_b    = (const float*)d_in[22];
    const float* cov_w   = (const float*)d_in[23];
    const float* cov_b   = (const float*)d_in[24];
    const float* wk_w    = (const float*)d_in[25];
    const float* wk_b    = (const float*)d_in[26];
    const float* pre_w   = (const float*)d_in[27];
    const float* pre_b   = (const float*)d_in[28];
    const float* gen_w   = (const float*)d_in[29];
    const float* gen_b   = (const float*)d_in[30];
    const float* pgen_w  = (const float*)d_in[31];
    const float* pgen_b  = (const float*)d_in[32];

    const int W = out_size / BB - 4*DD - 2*LL - 1;  // V + ex_size = 50200
    float* out     = (float*)d_out;
    float* o_final = out;
    float* o_h     = out + (size_t)BB*W;
    float* o_c     = o_h + BB*DD;
    float* o_wc    = o_c + BB*DD;
    float* o_attn  = o_wc + BB*2*DD;
    float* o_cov   = o_attn + BB*LL;
    float* o_pgen  = o_cov + BB*LL;

    // workspace
    float* W_actT   = (float*)d_ws;                  // 1280*64 floats
    float* W_whT    = W_actT + 1280*64;              // B*D
    float* W_wcT0   = W_whT + BB*DD;                 // B*D
    float* W_q      = W_wcT0 + BB*DD;                // B*D
    float* W_e      = W_q + BB*DD;                   // B*L  (exp(score))
    float* W_S      = W_e + BB*LL;                   // B    (sum exp)
    float* W_wcp    = W_S + BB;                      // B*512 (unnormalized wc)
    float* W_m      = W_wcp + BB*512;                // B
    float* W_s      = W_m + BB;                      // B
    float* W_u      = W_s + BB;                      // D
    float* W_v2     = W_u + DD;                      // D
    float* W_blkM   = W_v2 + DD;                     // B*NB
    float* W_blkS   = W_blkM + (size_t)BB*NB;        // B*NB
    short* W_wb     = (short*)(W_blkS + (size_t)BB*NB);  // 64*2048 shorts
    short* W_pgb    = (short*)(W_wb + 64*2048);          // B*D bf16
    short* W_lg     = W_pgb + BB*DD;                     // B*VV bf16 logits

    k_front1<<<dim3(DD,4), 256, 0, stream>>>(inp, hh, hc, prev, emb_w, lin_w, lin_b,
                                             rhw, rhb, rcw, rcb, step_p,
                                             wk_w, wk_b, cov_w, cov_b,
                                             W_actT, W_whT, W_wcT0, W_wb, W_u, W_v2,
                                             W_wcp, W_S);
    k_gl<<<DD, 256, 0, stream>>>(W_actT, W_whT, W_wcT0, w_ih, w_hh, b_ih, b_hh,
                                 o_h, o_c, W_actT);
    k_q2<<<DD, 256, 0, stream>>>(W_actT, wq_w, wq_b, W_q);
    k_score_mfma<<<dim3(13, BB), 1024, 0, stream>>>(enc, W_wb, W_u, W_v2, W_q, cov, pmask,
                                                    W_e, W_S, W_wcp);
    k_attn<<<BB, 512, 0, stream>>>(W_e, W_S, cov, o_attn, o_cov);
    k_tr<<<8, 256, 0, stream>>>(W_wcp, W_S, o_wc, W_actT);
    k_pregen<<<DD, 256, 0, stream>>>(W_actT, pre_w, pre_b, pgen_w, pgen_b, W_pgb, o_pgen);
    k_gen_mfma<<<NB, 256, 0, stream>>>(W_pgb, gen_w, gen_b, W_lg, W_blkM, W_blkS);
    k_vred<<<BB, 256, 0, stream>>>(W_blkM, W_blkS, W_m, W_s);
    k_final<<<(int)(((size_t)BB*W+255)/256), 256, 0, stream>>>(W_lg, o_final, W_m, W_s, o_pgen, W);
    k_scatter<<<(BB*LL+255)/256, 256, 0, stream>>>(o_final, ext, o_attn, o_pgen, W);
}